// Round 1
// baseline (17223.003 us; speedup 1.0000x reference)
//
#include <hip/hip_runtime.h>
#include <hip/hip_bf16.h>
#include <math.h>

#define PIX  2304   // 48*48
#define CCH  256

__device__ __forceinline__ float sigmoidf_(float x){ return 1.f/(1.f+__expf(-x)); }

// ---------------- generic strided GEMM: C[m][n] = sum_k A[m][k]*B[k][n] ----------------
#define GTS 64
#define GKT 16

__global__ __launch_bounds__(256) void gemm_k(
    const float* __restrict__ A, const float* __restrict__ B, float* __restrict__ C,
    int M, int N, int K,
    long sAm, long sAk, long sBk, long sBn, long sCm, long sCn,
    long bA, long bB, long bC)
{
    A += (long)blockIdx.z * bA; B += (long)blockIdx.z * bB; C += (long)blockIdx.z * bC;
    __shared__ float As[GKT][GTS+4];
    __shared__ float Bs[GKT][GTS+4];
    const int tid = threadIdx.x;
    const int tx = tid & 15, ty = tid >> 4;
    const long bm = (long)blockIdx.x * GTS, bn = (long)blockIdx.y * GTS;
    float acc[4][4] = {};
    for (int k0 = 0; k0 < K; k0 += GKT) {
        if (sAk == 1) {              // k contiguous -> k-fastest load mapping
            #pragma unroll
            for (int u = 0; u < 4; ++u) {
                int e = tid + u*256; int kk = e & 15; int mm = e >> 4;
                long gm = bm + mm, gk = k0 + kk;
                As[kk][mm] = (gm < M && gk < K) ? A[gm*sAm + gk] : 0.f;
            }
        } else {                     // m contiguous (or neither) -> m-fastest
            #pragma unroll
            for (int u = 0; u < 4; ++u) {
                int e = tid + u*256; int mm = e & 63; int kk = e >> 6;
                long gm = bm + mm, gk = k0 + kk;
                As[kk][mm] = (gm < M && gk < K) ? A[gm*sAm + gk*sAk] : 0.f;
            }
        }
        if (sBn == 1) {
            #pragma unroll
            for (int u = 0; u < 4; ++u) {
                int e = tid + u*256; int nn = e & 63; int kk = e >> 6;
                long gn = bn + nn, gk = k0 + kk;
                Bs[kk][nn] = (gn < N && gk < K) ? B[gk*sBk + gn] : 0.f;
            }
        } else {
            #pragma unroll
            for (int u = 0; u < 4; ++u) {
                int e = tid + u*256; int kk = e & 15; int nn = e >> 4;
                long gn = bn + nn, gk = k0 + kk;
                Bs[kk][nn] = (gn < N && gk < K) ? B[gk*sBk + gn*sBn] : 0.f;
            }
        }
        __syncthreads();
        #pragma unroll
        for (int kk = 0; kk < GKT; ++kk) {
            float4 a4 = *(const float4*)&As[kk][ty*4];
            float4 b4 = *(const float4*)&Bs[kk][tx*4];
            float av[4] = {a4.x, a4.y, a4.z, a4.w};
            float bv[4] = {b4.x, b4.y, b4.z, b4.w};
            #pragma unroll
            for (int i2 = 0; i2 < 4; ++i2)
                #pragma unroll
                for (int j2 = 0; j2 < 4; ++j2)
                    acc[i2][j2] += av[i2]*bv[j2];
        }
        __syncthreads();
    }
    #pragma unroll
    for (int i2 = 0; i2 < 4; ++i2)
        #pragma unroll
        for (int j2 = 0; j2 < 4; ++j2) {
            long gm = bm + ty*4 + i2, gn = bn + tx*4 + j2;
            if (gm < M && gn < N) C[gm*sCm + gn*sCn] = acc[i2][j2];
        }
}

// ---------------- backbone: 8x8 stride-8 VALID conv, 3->256ch, ReLU; writes v and h ----------------
__global__ __launch_bounds__(256) void backbone_k(
    const float* __restrict__ frames, const float* __restrict__ W,
    const float* __restrict__ bias, float* __restrict__ v, float* __restrict__ h)
{
    __shared__ float wl[3*64*4];  // [ci][k][o4]
    const int n = blockIdx.z, o0 = blockIdx.y * 4;
    const int p = blockIdx.x * 256 + threadIdx.x;
    const int y = p / 48, x = p % 48;
    for (int e = threadIdx.x; e < 768; e += 256) {
        int o_sel = e / 192, rem = e % 192, ci = rem / 64, k = rem % 64;
        wl[(ci*64 + k)*4 + o_sel] = W[((long)(o0 + o_sel)*3 + ci)*64 + k];
    }
    __syncthreads();
    float acc[4] = {0.f, 0.f, 0.f, 0.f};
    for (int ci = 0; ci < 3; ++ci) {
        const float* src = frames + (((long)n*3 + ci)*384) * 384;
        #pragma unroll
        for (int k = 0; k < 64; ++k) {
            int ky = k >> 3, kx = k & 7;
            float iv = src[(8*y + ky)*384 + 8*x + kx];
            float4 w = ((const float4*)wl)[ci*64 + k];
            acc[0] += iv*w.x; acc[1] += iv*w.y; acc[2] += iv*w.z; acc[3] += iv*w.w;
        }
    }
    #pragma unroll
    for (int oo = 0; oo < 4; ++oo) {
        float r = fmaxf(acc[oo] + bias[o0 + oo], 0.f);
        long idx = ((long)n*CCH + o0 + oo)*PIX + p;
        v[idx] = r; h[idx] = r;
    }
}

// ---------------- row softmax, in place, rows of length 2304 ----------------
__global__ __launch_bounds__(256) void softmax_k(float* __restrict__ E)
{
    __shared__ float red[4];
    __shared__ float red2[4];
    const long base = (long)blockIdx.x * PIX;
    const int tid = threadIdx.x;
    float vv[9];
    float mx = -1e30f;
    #pragma unroll
    for (int u = 0; u < 9; ++u) { vv[u] = E[base + tid + u*256]; mx = fmaxf(mx, vv[u]); }
    for (int off = 32; off; off >>= 1) mx = fmaxf(mx, __shfl_xor(mx, off));
    if ((tid & 63) == 0) red[tid >> 6] = mx;
    __syncthreads();
    mx = fmaxf(fmaxf(red[0], red[1]), fmaxf(red[2], red[3]));
    float s = 0.f;
    #pragma unroll
    for (int u = 0; u < 9; ++u) { vv[u] = __expf(vv[u] - mx); s += vv[u]; }
    for (int off = 32; off; off >>= 1) s += __shfl_xor(s, off);
    if ((tid & 63) == 0) red2[tid >> 6] = s;
    __syncthreads();
    s = red2[0] + red2[1] + red2[2] + red2[3];
    float inv = 1.f / s;
    #pragma unroll
    for (int u = 0; u < 9; ++u) E[base + tid + u*256] = vv[u]*inv;
}

// ---------------- gate + aggregate: magg (+)= sigmoid(G + gb[c]) * M ----------------
__global__ __launch_bounds__(256) void gate_agg_k(
    const float* __restrict__ G, const float* __restrict__ Mb,
    const float* __restrict__ gb, float* __restrict__ magg, int store)
{
    int idx = blockIdx.x*256 + threadIdx.x;
    int c = idx / PIX;
    float val = sigmoidf_(G[idx] + gb[c]) * Mb[idx];
    if (store) magg[idx] = val; else magg[idx] += val;
}

// ---------------- 3x3 SAME conv, 512ch (two concatenated 256 sources) -> 256ch ----------------
// act: 0 none, 1 sigmoid, 2 tanh, 3 relu
__global__ __launch_bounds__(256) void conv3x3_k(
    const float* __restrict__ in0, const float* __restrict__ in1,
    const float* __restrict__ W, const float* __restrict__ bias,
    float* __restrict__ out, int act)
{
    __shared__ float wl[128*9*4];   // [ci_local][k][o4]
    const int n = blockIdx.z, o0 = blockIdx.y * 4;
    const int p = blockIdx.x * 256 + threadIdx.x;
    const int y = p / 48, x = p % 48;
    float acc[4] = {0.f, 0.f, 0.f, 0.f};
    for (int c0 = 0; c0 < 512; c0 += 128) {
        for (int e = threadIdx.x; e < 128*9*4; e += 256) {
            int o_sel = e / (128*9), rem = e % (128*9), ci_l = rem / 9, k = rem % 9;
            wl[(ci_l*9 + k)*4 + o_sel] = W[((long)(o0 + o_sel)*512 + (c0 + ci_l))*9 + k];
        }
        __syncthreads();
        const float* srcp = (c0 < 256) ? in0 : in1;
        const int cb = (c0 < 256) ? c0 : (c0 - 256);
        for (int ci_l = 0; ci_l < 128; ++ci_l) {
            const float* src = srcp + ((long)n*CCH + cb + ci_l)*PIX;
            float iv[9];
            #pragma unroll
            for (int dy = 0; dy < 3; ++dy) {
                int yy = y + dy - 1;
                #pragma unroll
                for (int dx = 0; dx < 3; ++dx) {
                    int xx = x + dx - 1;
                    iv[dy*3+dx] = (yy >= 0 && yy < 48 && xx >= 0 && xx < 48) ? src[yy*48 + xx] : 0.f;
                }
            }
            const float4* wrow = (const float4*)&wl[ci_l*36];
            #pragma unroll
            for (int k = 0; k < 9; ++k) {
                float4 w = wrow[k];
                acc[0] += iv[k]*w.x; acc[1] += iv[k]*w.y; acc[2] += iv[k]*w.z; acc[3] += iv[k]*w.w;
            }
        }
        __syncthreads();
    }
    #pragma unroll
    for (int oo = 0; oo < 4; ++oo) {
        float r = acc[oo] + bias[o0 + oo];
        if (act == 1) r = sigmoidf_(r);
        else if (act == 2) r = tanhf(r);
        else if (act == 3) r = fmaxf(r, 0.f);
        out[((long)n*CCH + o0 + oo)*PIX + p] = r;
    }
}

// ---------------- elementwise ----------------
__global__ __launch_bounds__(256) void rh_k(const float* __restrict__ rg, const float* __restrict__ h,
                                            float* __restrict__ rh)
{
    int idx = blockIdx.x*256 + threadIdx.x;
    rh[idx] = rg[idx]*h[idx];
}

__global__ __launch_bounds__(256) void hupd_k(const float* __restrict__ zg, const float* __restrict__ hc,
                                              float* __restrict__ h)
{
    int idx = blockIdx.x*256 + threadIdx.x;
    float z = zg[idx];
    h[idx] = (1.f - z)*h[idx] + z*hc[idx];
}

// ---------------- final 3x3 conv, 256ch -> 1ch ----------------
__global__ __launch_bounds__(256) void mask_k(const float* __restrict__ yin, const float* __restrict__ W,
                                              const float* __restrict__ bias, float* __restrict__ out)
{
    __shared__ float wl[2304];  // 256*9
    for (int e = threadIdx.x; e < 2304; e += 256) wl[e] = W[e];
    __syncthreads();
    int id = blockIdx.x*256 + threadIdx.x;   // over 3*2304
    int n = id / PIX, p = id % PIX;
    int y = p / 48, x = p % 48;
    float acc = bias[0];
    for (int ci = 0; ci < 256; ++ci) {
        const float* src = yin + ((long)n*CCH + ci)*PIX;
        #pragma unroll
        for (int dy = 0; dy < 3; ++dy) {
            int yy = y + dy - 1;
            #pragma unroll
            for (int dx = 0; dx < 3; ++dx) {
                int xx = x + dx - 1;
                float iv = (yy >= 0 && yy < 48 && xx >= 0 && xx < 48) ? src[yy*48 + xx] : 0.f;
                acc += iv * wl[ci*9 + dy*3 + dx];
            }
        }
    }
    out[id] = acc;
}

extern "C" void kernel_launch(void* const* d_in, const int* in_sizes, int n_in,
                              void* d_out, int out_size, void* d_ws, size_t ws_size,
                              hipStream_t stream)
{
    const float* frames     = (const float*)d_in[0];
    const float* backbone_w = (const float*)d_in[1];
    const float* backbone_b = (const float*)d_in[2];
    const float* W_intra    = (const float*)d_in[3];
    const float* W_inter    = (const float*)d_in[4];
    const float* gate_w     = (const float*)d_in[5];
    const float* gate_b     = (const float*)d_in[6];
    const float* Wz         = (const float*)d_in[7];
    const float* bz         = (const float*)d_in[8];
    const float* Wr         = (const float*)d_in[9];
    const float* br         = (const float*)d_in[10];
    const float* Wh         = (const float*)d_in[11];
    const float* bh         = (const float*)d_in[12];
    const float* ro_w1      = (const float*)d_in[13];
    const float* ro_b1      = (const float*)d_in[14];
    const float* ro_w2      = (const float*)d_in[15];
    const float* ro_b2      = (const float*)d_in[16];
    float* out = (float*)d_out;
    float* ws  = (float*)d_ws;

    const long CP  = (long)CCH * PIX;        // 589824
    const long NCP = 3 * CP;                 // 1769472
    float* v    = ws;
    float* h    = ws + 1*NCP;
    float* t    = ws + 2*NCP;
    float* ti   = ws + 3*NCP;
    float* magg = ws + 4*NCP;
    float* zg   = ws + 5*NCP;
    float* rg   = ws + 6*NCP;
    float* rh   = ws + 7*NCP;
    float* hc   = ws + 8*NCP;
    float* E    = ws + 9*NCP;                // 2304*2304 = 3*NCP
    float* Mb   = ws + 12*NCP;
    float* Gb   = ws + 12*NCP + CP;

    dim3 b256(256);

    backbone_k<<<dim3(9, 64, 3), b256, 0, stream>>>(frames, backbone_w, backbone_b, v, h);

    for (int it = 0; it < 3; ++it) {
        // t[i][d][p] = sum_c h[i][c][p] * W_inter[c][d]   (batched over i)
        gemm_k<<<dim3(4, 36, 3), b256, 0, stream>>>(W_inter, h, t, 256, PIX, 256,
                                                    1L, 256L, (long)PIX, 1L, (long)PIX, 1L,
                                                    0L, CP, CP);
        gemm_k<<<dim3(4, 36, 3), b256, 0, stream>>>(W_intra, h, ti, 256, PIX, 256,
                                                    1L, 256L, (long)PIX, 1L, (long)PIX, 1L,
                                                    0L, CP, CP);
        for (int pair = 0; pair < 9; ++pair) {
            int i = pair / 3, j = pair % 3;
            const float* Ae = ((i == j) ? ti : t) + (long)i*CP;
            // E[p][q] = sum_d Ae[d][p] * h[j][d][q]
            gemm_k<<<dim3(36, 36, 1), b256, 0, stream>>>(Ae, h + (long)j*CP, E, PIX, PIX, 256,
                                                         1L, (long)PIX, (long)PIX, 1L, (long)PIX, 1L,
                                                         0L, 0L, 0L);
            softmax_k<<<PIX, b256, 0, stream>>>(E);
            // Mb[c][p] = sum_q h[j][c][q] * attn[p][q]
            gemm_k<<<dim3(4, 36, 1), b256, 0, stream>>>(h + (long)j*CP, E, Mb, 256, PIX, PIX,
                                                        (long)PIX, 1L, 1L, (long)PIX, (long)PIX, 1L,
                                                        0L, 0L, 0L);
            // Gb[c'][p] = sum_c gate_w[c'][c] * Mb[c][p]
            gemm_k<<<dim3(4, 36, 1), b256, 0, stream>>>(gate_w, Mb, Gb, 256, PIX, 256,
                                                        256L, 1L, (long)PIX, 1L, (long)PIX, 1L,
                                                        0L, 0L, 0L);
            gate_agg_k<<<(int)(CP/256), b256, 0, stream>>>(Gb, Mb, gate_b, magg + (long)i*CP, (j == 0) ? 1 : 0);
        }
        // ConvGRU
        conv3x3_k<<<dim3(9, 64, 3), b256, 0, stream>>>(magg, h, Wz, bz, zg, 1);
        conv3x3_k<<<dim3(9, 64, 3), b256, 0, stream>>>(magg, h, Wr, br, rg, 1);
        rh_k<<<(int)(NCP/256), b256, 0, stream>>>(rg, h, rh);
        conv3x3_k<<<dim3(9, 64, 3), b256, 0, stream>>>(magg, rh, Wh, bh, hc, 2);
        hupd_k<<<(int)(NCP/256), b256, 0, stream>>>(zg, hc, h);
    }

    // readout: y = relu(conv3x3(concat(h, v))), reuse t as y buffer
    conv3x3_k<<<dim3(9, 64, 3), b256, 0, stream>>>(h, v, ro_w1, ro_b1, t, 3);
    mask_k<<<27, b256, 0, stream>>>(t, ro_w2, ro_b2, out);
}

// Round 2
// 6019.604 us; speedup vs baseline: 2.8612x; 2.8612x over previous
//
#include <hip/hip_runtime.h>
#include <hip/hip_bf16.h>
#include <math.h>

#define PIX 2304
#define CCH 256
#define CP  589824      // CCH*PIX
#define NCP 1769472     // 3*CP
#define PP  5308416     // PIX*PIX

typedef __hip_bfloat16 bf16;
typedef __attribute__((ext_vector_type(8))) short bf16x8;
typedef __attribute__((ext_vector_type(4))) float f32x4;

__device__ __forceinline__ float sigmoidf_(float x){ return 1.f/(1.f+__expf(-x)); }

__device__ __forceinline__ void gl_lds16(const bf16* g, bf16* lds){
    __builtin_amdgcn_global_load_lds(
        (const __attribute__((address_space(1))) void*)g,
        (__attribute__((address_space(3))) void*)lds, 16, 0, 0);
}

// ---------------- bf16 MFMA GEMM, BT layout: C[m][n] = sum_k A[m][k]*B[n][k] ----------------
// A: M x K row-major (lda), B: N x K row-major (ldb). M,N multiples of 128, K of 64.
// EPI 0: write bf16 C (ldc). EPI 2: write fp32 sigmoid(acc+bias[m]) * aux[n*auxld+m].
template<int EPI>
__global__ __launch_bounds__(256) void mgemm_k(
    const bf16* __restrict__ A0, const bf16* __restrict__ A1, int diagz,
    const bf16* __restrict__ B, void* __restrict__ Cv,
    const bf16* __restrict__ aux, const float* __restrict__ bias,
    int M, int N, int K, int lda, int ldb, int ldc, int auxld,
    long bsA, long bsB, long bsC, long bsAux)
{
    __shared__ bf16 As[128*64];
    __shared__ bf16 Bs[128*64];
    const int z = blockIdx.z;
    const bf16* Ap = ((z==diagz)?A1:A0) + z*bsA + (long)blockIdx.x*128*lda;
    const bf16* Bp = B + z*bsB + (long)blockIdx.y*128*ldb;
    const int tid = threadIdx.x, l = tid & 63;
    const int wvu = tid & ~63;                 // wave*64 (wave-uniform)
    const int wr = tid>>7, wc = (tid>>6)&1;    // 2x2 wave grid, 64x64 each
    f32x4 acc[4][4];
    #pragma unroll
    for (int i=0;i<4;++i)
        #pragma unroll
        for (int j=0;j<4;++j) acc[i][j] = (f32x4){0.f,0.f,0.f,0.f};

    for (int k0=0;k0<K;k0+=64){
        #pragma unroll
        for (int u=0;u<4;++u){
            int idx = u*256 + tid;             // chunk id; row=idx>>3, col8=idx&7
            gl_lds16(Ap + (long)(idx>>3)*lda + k0 + (idx&7)*8, As + (u*256+wvu)*8);
        }
        #pragma unroll
        for (int u=0;u<4;++u){
            int idx = u*256 + tid;
            gl_lds16(Bp + (long)(idx>>3)*ldb + k0 + (idx&7)*8, Bs + (u*256+wvu)*8);
        }
        __syncthreads();
        #pragma unroll
        for (int ks=0;ks<64;ks+=32){
            bf16x8 af[4], bft[4];
            #pragma unroll
            for (int i=0;i<4;++i)
                af[i] = *(const bf16x8*)(As + (wr*64 + i*16 + (l&15))*64 + ks + (l>>4)*8);
            #pragma unroll
            for (int j=0;j<4;++j)
                bft[j] = *(const bf16x8*)(Bs + (wc*64 + j*16 + (l&15))*64 + ks + (l>>4)*8);
            #pragma unroll
            for (int i=0;i<4;++i)
                #pragma unroll
                for (int j=0;j<4;++j)
                    acc[i][j] = __builtin_amdgcn_mfma_f32_16x16x32_bf16(af[i], bft[j], acc[i][j], 0,0,0);
        }
        __syncthreads();
    }

    const int mb = blockIdx.x*128 + wr*64, nb = blockIdx.y*128 + wc*64;
    #pragma unroll
    for (int i=0;i<4;++i)
        #pragma unroll
        for (int j=0;j<4;++j){
            int gm0 = mb + i*16 + ((l>>4)<<2);
            int gn  = nb + j*16 + (l&15);
            #pragma unroll
            for (int r=0;r<4;++r){
                int gm = gm0 + r;
                float vacc = acc[i][j][r];
                if (EPI==0){
                    ((bf16*)Cv)[z*bsC + (long)gm*ldc + gn] = __float2bfloat16(vacc);
                } else {
                    float g = sigmoidf_(vacc + bias[gm]);
                    float mv = __bfloat162float(aux[z*bsAux + (long)gn*auxld + gm]);
                    ((float*)Cv)[z*bsC + (long)gm*ldc + gn] = g*mv;
                }
            }
        }
}

// ---------------- h (C,P) fp32 -> hcp16 (C,P) bf16 + hp16 (P,C) bf16 ----------------
__global__ __launch_bounds__(256) void prep_h_k(const float* __restrict__ h,
        bf16* __restrict__ hcp, bf16* __restrict__ hp)
{
    __shared__ float tile[64][65];
    const int i = blockIdx.z, p0 = blockIdx.x*64, c0 = blockIdx.y*64;
    const int t = threadIdx.x, tx = t&63, tq = t>>6;
    const float* src = h + (long)i*CP;
    #pragma unroll
    for (int s=0;s<16;++s){
        int r = tq + s*4;
        float v = src[(long)(c0+r)*PIX + p0 + tx];
        tile[r][tx] = v;
        hcp[(long)i*CP + (long)(c0+r)*PIX + p0 + tx] = __float2bfloat16(v);
    }
    __syncthreads();
    #pragma unroll
    for (int s=0;s<16;++s){
        int r = tq + s*4;
        hp[(long)i*CP + (long)(p0+r)*256 + c0 + tx] = __float2bfloat16(tile[tx][r]);
    }
}

// ---------------- weight conversion: W_inter^T, W_intra^T, gate_w to bf16 ----------------
__global__ __launch_bounds__(256) void convert_w_k(const float* __restrict__ wint,
    const float* __restrict__ wintra, const float* __restrict__ gw, bf16* __restrict__ o)
{
    int t = blockIdx.x*256 + threadIdx.x;   // 65536
    int d = t >> 8, c = t & 255;
    o[t]          = __float2bfloat16(wint[c*256 + d]);
    o[65536 + t]  = __float2bfloat16(wintra[c*256 + d]);
    o[131072 + t] = __float2bfloat16(gw[t]);
}

// ---------------- row softmax in place on bf16, rows of 2304 ----------------
__global__ __launch_bounds__(256) void softmax16_k(bf16* __restrict__ E)
{
    __shared__ float red[4], red2[4];
    const long base = (long)blockIdx.x * PIX;
    const int tid = threadIdx.x;
    float vv[9]; float mx = -1e30f;
    #pragma unroll
    for (int u=0;u<9;++u){ vv[u] = __bfloat162float(E[base + tid + u*256]); mx = fmaxf(mx, vv[u]); }
    for (int off=32; off; off>>=1) mx = fmaxf(mx, __shfl_xor(mx, off));
    if ((tid&63)==0) red[tid>>6] = mx;
    __syncthreads();
    mx = fmaxf(fmaxf(red[0],red[1]), fmaxf(red[2],red[3]));
    float s = 0.f;
    #pragma unroll
    for (int u=0;u<9;++u){ vv[u] = __expf(vv[u]-mx); s += vv[u]; }
    for (int off=32; off; off>>=1) s += __shfl_xor(s, off);
    if ((tid&63)==0) red2[tid>>6] = s;
    __syncthreads();
    s = red2[0]+red2[1]+red2[2]+red2[3];
    float inv = 1.f/s;
    #pragma unroll
    for (int u=0;u<9;++u) E[base + tid + u*256] = __float2bfloat16(vv[u]*inv);
}

// ---------------- sum 3 gated message buffers (C,P) -> magg_i ----------------
__global__ __launch_bounds__(256) void gatesum_k(const float* __restrict__ g, float* __restrict__ out)
{
    int x = blockIdx.x*256 + threadIdx.x;   // CP/4 elems of float4
    float4 a = ((const float4*)g)[x];
    float4 b = ((const float4*)g)[x + CP/4];
    float4 c = ((const float4*)g)[x + CP/2];
    float4 r; r.x=a.x+b.x+c.x; r.y=a.y+b.y+c.y; r.z=a.z+b.z+c.z; r.w=a.w+b.w+c.w;
    ((float4*)out)[x] = r;
}

// ---------------- backbone: 8x8 stride-8 conv, 3->256ch, ReLU -> v,h (C,P) ----------------
__global__ __launch_bounds__(256) void backbone_k(
    const float* __restrict__ frames, const float* __restrict__ W,
    const float* __restrict__ bias, float* __restrict__ v, float* __restrict__ h)
{
    __shared__ float wl[3*64*4];
    const int n = blockIdx.z, o0 = blockIdx.y * 4;
    const int p = blockIdx.x * 256 + threadIdx.x;
    const int y = p / 48, x = p % 48;
    for (int e = threadIdx.x; e < 768; e += 256) {
        int o_sel = e / 192, rem = e % 192, ci = rem / 64, k = rem % 64;
        wl[(ci*64 + k)*4 + o_sel] = W[((long)(o0 + o_sel)*3 + ci)*64 + k];
    }
    __syncthreads();
    float acc[4] = {0.f,0.f,0.f,0.f};
    for (int ci = 0; ci < 3; ++ci) {
        const float* src = frames + (((long)n*3 + ci)*384) * 384;
        #pragma unroll
        for (int k = 0; k < 64; ++k) {
            int ky = k >> 3, kx = k & 7;
            float iv = src[(8*y + ky)*384 + 8*x + kx];
            float4 w = ((const float4*)wl)[ci*64 + k];
            acc[0] += iv*w.x; acc[1] += iv*w.y; acc[2] += iv*w.z; acc[3] += iv*w.w;
        }
    }
    #pragma unroll
    for (int oo = 0; oo < 4; ++oo) {
        float r = fmaxf(acc[oo] + bias[o0 + oo], 0.f);
        long idx = ((long)n*CCH + o0 + oo)*PIX + p;
        v[idx] = r; h[idx] = r;
    }
}

// ---------------- 3x3 SAME conv, concat(in0,in1) 512ch -> 256ch, fp32 ----------------
__global__ __launch_bounds__(256) void conv3x3_k(
    const float* __restrict__ in0, const float* __restrict__ in1,
    const float* __restrict__ W, const float* __restrict__ bias,
    float* __restrict__ out, int act)
{
    __shared__ float wl[128*9*4];
    const int n = blockIdx.z, o0 = blockIdx.y * 4;
    const int p = blockIdx.x * 256 + threadIdx.x;
    const int y = p / 48, x = p % 48;
    float acc[4] = {0.f,0.f,0.f,0.f};
    for (int c0 = 0; c0 < 512; c0 += 128) {
        for (int e = threadIdx.x; e < 128*9*4; e += 256) {
            int o_sel = e / (128*9), rem = e % (128*9), ci_l = rem / 9, k = rem % 9;
            wl[(ci_l*9 + k)*4 + o_sel] = W[((long)(o0 + o_sel)*512 + (c0 + ci_l))*9 + k];
        }
        __syncthreads();
        const float* srcp = (c0 < 256) ? in0 : in1;
        const int cb = (c0 < 256) ? c0 : (c0 - 256);
        for (int ci_l = 0; ci_l < 128; ++ci_l) {
            const float* src = srcp + ((long)n*CCH + cb + ci_l)*PIX;
            float iv[9];
            #pragma unroll
            for (int dy = 0; dy < 3; ++dy) {
                int yy = y + dy - 1;
                #pragma unroll
                for (int dx = 0; dx < 3; ++dx) {
                    int xx = x + dx - 1;
                    iv[dy*3+dx] = (yy >= 0 && yy < 48 && xx >= 0 && xx < 48) ? src[yy*48 + xx] : 0.f;
                }
            }
            const float4* wrow = (const float4*)&wl[ci_l*36];
            #pragma unroll
            for (int k = 0; k < 9; ++k) {
                float4 w = wrow[k];
                acc[0] += iv[k]*w.x; acc[1] += iv[k]*w.y; acc[2] += iv[k]*w.z; acc[3] += iv[k]*w.w;
            }
        }
        __syncthreads();
    }
    #pragma unroll
    for (int oo = 0; oo < 4; ++oo) {
        float r = acc[oo] + bias[o0 + oo];
        if (act == 1) r = sigmoidf_(r);
        else if (act == 2) r = tanhf(r);
        else if (act == 3) r = fmaxf(r, 0.f);
        out[((long)n*CCH + o0 + oo)*PIX + p] = r;
    }
}

__global__ __launch_bounds__(256) void rh_k(const float* __restrict__ rg, const float* __restrict__ h,
                                            float* __restrict__ rh)
{
    int idx = blockIdx.x*256 + threadIdx.x;
    rh[idx] = rg[idx]*h[idx];
}

__global__ __launch_bounds__(256) void hupd_k(const float* __restrict__ zg, const float* __restrict__ hc,
                                              float* __restrict__ h)
{
    int idx = blockIdx.x*256 + threadIdx.x;
    float z = zg[idx];
    h[idx] = (1.f - z)*h[idx] + z*hc[idx];
}

// ---------------- final 3x3 conv, 256ch -> 1ch ----------------
__global__ __launch_bounds__(256) void mask_k(const float* __restrict__ yin, const float* __restrict__ W,
                                              const float* __restrict__ bias, float* __restrict__ out)
{
    __shared__ float wl[2304];
    for (int e = threadIdx.x; e < 2304; e += 256) wl[e] = W[e];
    __syncthreads();
    int id = blockIdx.x*256 + threadIdx.x;
    int n = id / PIX, p = id % PIX;
    int y = p / 48, x = p % 48;
    float acc = bias[0];
    for (int ci = 0; ci < 256; ++ci) {
        const float* src = yin + ((long)n*CCH + ci)*PIX;
        #pragma unroll
        for (int dy = 0; dy < 3; ++dy) {
            int yy = y + dy - 1;
            #pragma unroll
            for (int dx = 0; dx < 3; ++dx) {
                int xx = x + dx - 1;
                float iv = (yy >= 0 && yy < 48 && xx >= 0 && xx < 48) ? src[yy*48 + xx] : 0.f;
                acc += iv * wl[ci*9 + dy*3 + dx];
            }
        }
    }
    out[id] = acc;
}

extern "C" void kernel_launch(void* const* d_in, const int* in_sizes, int n_in,
                              void* d_out, int out_size, void* d_ws, size_t ws_size,
                              hipStream_t stream)
{
    const float* frames     = (const float*)d_in[0];
    const float* backbone_w = (const float*)d_in[1];
    const float* backbone_b = (const float*)d_in[2];
    const float* W_intra    = (const float*)d_in[3];
    const float* W_inter    = (const float*)d_in[4];
    const float* gate_w     = (const float*)d_in[5];
    const float* gate_b     = (const float*)d_in[6];
    const float* Wz         = (const float*)d_in[7];
    const float* bz         = (const float*)d_in[8];
    const float* Wr         = (const float*)d_in[9];
    const float* br         = (const float*)d_in[10];
    const float* Wh         = (const float*)d_in[11];
    const float* bh         = (const float*)d_in[12];
    const float* ro_w1      = (const float*)d_in[13];
    const float* ro_b1      = (const float*)d_in[14];
    const float* ro_w2      = (const float*)d_in[15];
    const float* ro_b2      = (const float*)d_in[16];
    float* out = (float*)d_out;
    float* ws  = (float*)d_ws;

    float* h    = ws + 0L*NCP;
    float* v    = ws + 1L*NCP;
    float* magg = ws + 2L*NCP;
    float* zg   = ws + 3L*NCP;
    float* rg   = ws + 4L*NCP;
    float* rhg  = ws + 5L*NCP;   // rh (GRU) / gated (attention) — phases don't overlap
    float* hcmb = ws + 6L*NCP;   // hc (GRU fp32) / Mb16 (attention bf16)
    float* E16f = ws + 7L*NCP;   // 3 * PIX*PIX bf16 = 7962624 floats
    float* hp16f  = E16f + 7962624;
    float* hcp16f = hp16f + 884736;
    float* t16f   = hcp16f + 884736;
    float* ti16f  = t16f + 884736;
    float* wbuff  = ti16f + 884736;  // 3*65536 bf16

    bf16* E16    = (bf16*)E16f;
    bf16* hp16   = (bf16*)hp16f;
    bf16* hcp16  = (bf16*)hcp16f;
    bf16* t16    = (bf16*)t16f;
    bf16* ti16   = (bf16*)ti16f;
    bf16* Mb16   = (bf16*)hcmb;
    float* hc    = hcmb;
    float* gated = rhg;
    bf16* Wint_t   = (bf16*)wbuff;
    bf16* Wintra_t = Wint_t + 65536;
    bf16* gatew16  = Wint_t + 131072;

    dim3 b256(256);

    backbone_k<<<dim3(9,64,3), b256, 0, stream>>>(frames, backbone_w, backbone_b, v, h);
    convert_w_k<<<dim3(256), b256, 0, stream>>>(W_inter, W_intra, gate_w, Wint_t);

    for (int it = 0; it < 3; ++it) {
        prep_h_k<<<dim3(36,4,3), b256, 0, stream>>>(h, hcp16, hp16);
        // t = hp * W_inter  (M=6912,N=256,K=256)
        mgemm_k<0><<<dim3(54,2,1), b256, 0, stream>>>(hp16, hp16, -1, Wint_t, t16,
            nullptr, nullptr, 6912,256,256, 256,256,256, 0, 0L,0L,0L,0L);
        mgemm_k<0><<<dim3(54,2,1), b256, 0, stream>>>(hp16, hp16, -1, Wintra_t, ti16,
            nullptr, nullptr, 6912,256,256, 256,256,256, 0, 0L,0L,0L,0L);
        for (int i = 0; i < 3; ++i) {
            // E_j[p][q] = sum_d A_i[p][d] * hp_j[q][d]; A = ti on diagonal pair
            mgemm_k<0><<<dim3(18,18,3), b256, 0, stream>>>(t16 + (long)i*CP, ti16 + (long)i*CP, i,
                hp16, E16, nullptr, nullptr,
                2304,2304,256, 256,256,2304, 0, 0L,(long)CP,(long)PP,0L);
            softmax16_k<<<dim3(3*PIX), b256, 0, stream>>>(E16);
            // Mb_j[p][c] = sum_q attn_j[p][q] * hcp_j[c][q]
            mgemm_k<0><<<dim3(18,2,3), b256, 0, stream>>>(E16, E16, -1,
                hcp16, Mb16, nullptr, nullptr,
                2304,256,2304, 2304,2304,256, 0, (long)PP,(long)CP,(long)PIX*256,0L);
            // gated_j[c'][p] = sigmoid(sum_c gate_w[c'][c]*Mb_j[p][c] + gb[c']) * Mb_j[p][c']
            mgemm_k<2><<<dim3(2,18,3), b256, 0, stream>>>(gatew16, gatew16, -1,
                Mb16, gated, Mb16, gate_b,
                256,2304,256, 256,256,PIX, 256, 0L,(long)PIX*256,(long)CP,(long)PIX*256);
            gatesum_k<<<dim3(576), b256, 0, stream>>>(gated, magg + (long)i*CP);
        }
        // ConvGRU (fp32, unchanged)
        conv3x3_k<<<dim3(9,64,3), b256, 0, stream>>>(magg, h, Wz, bz, zg, 1);
        conv3x3_k<<<dim3(9,64,3), b256, 0, stream>>>(magg, h, Wr, br, rg, 1);
        rh_k<<<dim3(6912), b256, 0, stream>>>(rg, h, rhg);
        conv3x3_k<<<dim3(9,64,3), b256, 0, stream>>>(magg, rhg, Wh, bh, hc, 2);
        hupd_k<<<dim3(6912), b256, 0, stream>>>(zg, hc, h);
    }

    // readout (zg reused as y buffer)
    conv3x3_k<<<dim3(9,64,3), b256, 0, stream>>>(h, v, ro_w1, ro_b1, zg, 3);
    mask_k<<<dim3(27), b256, 0, stream>>>(zg, ro_w2, ro_b2, out);
}

// Round 3
// 1982.611 us; speedup vs baseline: 8.6870x; 3.0362x over previous
//
#include <hip/hip_runtime.h>
#include <hip/hip_bf16.h>
#include <math.h>

#define PIX 2304
#define CCH 256
#define CP  589824      // CCH*PIX
#define NCP 1769472     // 3*CP
#define PP  5308416     // PIX*PIX
#define KC  4608        // conv K = 512*9

typedef __hip_bfloat16 bf16;
typedef __attribute__((ext_vector_type(8))) short bf16x8;
typedef __attribute__((ext_vector_type(4))) float f32x4;

__device__ __forceinline__ float sigmoidf_(float x){ return 1.f/(1.f+__expf(-x)); }

__device__ __forceinline__ void gl_lds16(const bf16* g, bf16* lds){
    __builtin_amdgcn_global_load_lds(
        (const __attribute__((address_space(1))) void*)g,
        (__attribute__((address_space(3))) void*)lds, 16, 0, 0);
}

// ---------------- bf16 MFMA GEMM, BT layout: C[m][n] = sum_k A[m][k]*B[n][k] ----------------
template<int EPI>
__global__ __launch_bounds__(256) void mgemm_k(
    const bf16* __restrict__ A0, const bf16* __restrict__ A1, int diagz,
    const bf16* __restrict__ B, void* __restrict__ Cv,
    const bf16* __restrict__ aux, const float* __restrict__ bias,
    int M, int N, int K, int lda, int ldb, int ldc, int auxld,
    long bsA, long bsB, long bsC, long bsAux)
{
    __shared__ bf16 As[128*64];
    __shared__ bf16 Bs[128*64];
    const int z = blockIdx.z;
    const bf16* Ap = ((z==diagz)?A1:A0) + z*bsA + (long)blockIdx.x*128*lda;
    const bf16* Bp = B + z*bsB + (long)blockIdx.y*128*ldb;
    const int tid = threadIdx.x, l = tid & 63;
    const int wvu = tid & ~63;
    const int wr = tid>>7, wc = (tid>>6)&1;
    f32x4 acc[4][4];
    #pragma unroll
    for (int i=0;i<4;++i)
        #pragma unroll
        for (int j=0;j<4;++j) acc[i][j] = (f32x4){0.f,0.f,0.f,0.f};

    for (int k0=0;k0<K;k0+=64){
        #pragma unroll
        for (int u=0;u<4;++u){
            int idx = u*256 + tid;
            gl_lds16(Ap + (long)(idx>>3)*lda + k0 + (idx&7)*8, As + (u*256+wvu)*8);
        }
        #pragma unroll
        for (int u=0;u<4;++u){
            int idx = u*256 + tid;
            gl_lds16(Bp + (long)(idx>>3)*ldb + k0 + (idx&7)*8, Bs + (u*256+wvu)*8);
        }
        __syncthreads();
        #pragma unroll
        for (int ks=0;ks<64;ks+=32){
            bf16x8 af[4], bft[4];
            #pragma unroll
            for (int i=0;i<4;++i)
                af[i] = *(const bf16x8*)(As + (wr*64 + i*16 + (l&15))*64 + ks + (l>>4)*8);
            #pragma unroll
            for (int j=0;j<4;++j)
                bft[j] = *(const bf16x8*)(Bs + (wc*64 + j*16 + (l&15))*64 + ks + (l>>4)*8);
            #pragma unroll
            for (int i=0;i<4;++i)
                #pragma unroll
                for (int j=0;j<4;++j)
                    acc[i][j] = __builtin_amdgcn_mfma_f32_16x16x32_bf16(af[i], bft[j], acc[i][j], 0,0,0);
        }
        __syncthreads();
    }

    const int mb = blockIdx.x*128 + wr*64, nb = blockIdx.y*128 + wc*64;
    #pragma unroll
    for (int i=0;i<4;++i)
        #pragma unroll
        for (int j=0;j<4;++j){
            int gm0 = mb + i*16 + ((l>>4)<<2);
            int gn  = nb + j*16 + (l&15);
            #pragma unroll
            for (int r=0;r<4;++r){
                int gm = gm0 + r;
                float vacc = acc[i][j][r];
                if (EPI==0){
                    ((bf16*)Cv)[z*bsC + (long)gm*ldc + gn] = __float2bfloat16(vacc);
                } else {
                    float g = sigmoidf_(vacc + bias[gm]);
                    float mv = __bfloat162float(aux[z*bsAux + (long)gn*auxld + gm]);
                    ((float*)Cv)[z*bsC + (long)gm*ldc + gn] = g*mv;
                }
            }
        }
}

// ---------------- conv-as-GEMM with activation epilogue ----------------
// A: Mx4608 bf16 (k = tap*512+ci). B: im2col rows (6912 x 4608) bf16.
// ACT 1: sigmoid, dual output (m<256 -> o0/b0, else o1/b1). ACT 2: tanh. ACT 3: relu.
template<int ACT>
__global__ __launch_bounds__(256) void cgemm_k(
    const bf16* __restrict__ A, const bf16* __restrict__ B,
    const float* __restrict__ b0, const float* __restrict__ b1,
    float* __restrict__ o0, float* __restrict__ o1)
{
    __shared__ bf16 As[128*64];
    __shared__ bf16 Bs[128*64];
    const bf16* Ap = A + (long)blockIdx.x*128*KC;
    const bf16* Bp = B + (long)blockIdx.y*128*KC;
    const int tid = threadIdx.x, l = tid & 63;
    const int wvu = tid & ~63;
    const int wr = tid>>7, wc = (tid>>6)&1;
    f32x4 acc[4][4];
    #pragma unroll
    for (int i=0;i<4;++i)
        #pragma unroll
        for (int j=0;j<4;++j) acc[i][j] = (f32x4){0.f,0.f,0.f,0.f};

    for (int k0=0;k0<KC;k0+=64){
        #pragma unroll
        for (int u=0;u<4;++u){
            int idx = u*256 + tid;
            gl_lds16(Ap + (long)(idx>>3)*KC + k0 + (idx&7)*8, As + (u*256+wvu)*8);
        }
        #pragma unroll
        for (int u=0;u<4;++u){
            int idx = u*256 + tid;
            gl_lds16(Bp + (long)(idx>>3)*KC + k0 + (idx&7)*8, Bs + (u*256+wvu)*8);
        }
        __syncthreads();
        #pragma unroll
        for (int ks=0;ks<64;ks+=32){
            bf16x8 af[4], bft[4];
            #pragma unroll
            for (int i=0;i<4;++i)
                af[i] = *(const bf16x8*)(As + (wr*64 + i*16 + (l&15))*64 + ks + (l>>4)*8);
            #pragma unroll
            for (int j=0;j<4;++j)
                bft[j] = *(const bf16x8*)(Bs + (wc*64 + j*16 + (l&15))*64 + ks + (l>>4)*8);
            #pragma unroll
            for (int i=0;i<4;++i)
                #pragma unroll
                for (int j=0;j<4;++j)
                    acc[i][j] = __builtin_amdgcn_mfma_f32_16x16x32_bf16(af[i], bft[j], acc[i][j], 0,0,0);
        }
        __syncthreads();
    }

    const int mb = blockIdx.x*128 + wr*64, nb = blockIdx.y*128 + wc*64;
    #pragma unroll
    for (int i=0;i<4;++i)
        #pragma unroll
        for (int j=0;j<4;++j){
            int gm0 = mb + i*16 + ((l>>4)<<2);
            int gn  = nb + j*16 + (l&15);
            int img = gn / 2304, p = gn - img*2304;
            #pragma unroll
            for (int r=0;r<4;++r){
                int gm = gm0 + r;
                float vacc = acc[i][j][r];
                float* op; const float* bp; int co = gm;
                if (ACT==1){
                    if (co < 256){ op = o0; bp = b0; }
                    else { op = o1; bp = b1; co -= 256; }
                } else { op = o0; bp = b0; }
                float rv = vacc + bp[co];
                if (ACT==1) rv = sigmoidf_(rv);
                else if (ACT==2) rv = tanhf(rv);
                else rv = fmaxf(rv, 0.f);
                op[(long)img*CP + (long)co*PIX + p] = rv;
            }
        }
}

// ---------------- im2col: src (3,256,2304) fp32 -> dst (3*2304, 4608) bf16, k=tap*512+colofs+ci ----------------
__global__ __launch_bounds__(256) void im2col_k(const float* __restrict__ src,
        bf16* __restrict__ dst, int colofs)
{
    __shared__ float tile[64][163];
    const int p0 = blockIdx.x*64, cib = blockIdx.y*64, img = blockIdx.z;
    const int tid = threadIdx.x;
    const float* s = src + ((long)img*CCH + cib)*PIX;
    for (int e = tid; e < 64*162; e += 256){
        int ci_l = e / 162, off = e % 162;
        int gp = p0 + off - 49;
        tile[ci_l][off] = (gp >= 0 && gp < PIX) ? s[(long)ci_l*PIX + gp] : 0.f;
    }
    __syncthreads();
    const int ci_l = tid & 63, pg = tid >> 6;
    bf16* d = dst + ((long)img*PIX + p0)*KC + colofs + cib + ci_l;
    #pragma unroll
    for (int s8 = 0; s8 < 16; ++s8){
        int p_l = pg*16 + s8;
        int p = p0 + p_l, y = p / 48, x = p % 48;
        #pragma unroll
        for (int dy = 0; dy < 3; ++dy){
            int yy = y + dy - 1;
            #pragma unroll
            for (int dx = 0; dx < 3; ++dx){
                int xx = x + dx - 1;
                bool ok = (yy >= 0 && yy < 48 && xx >= 0 && xx < 48);
                float v = ok ? tile[ci_l][p_l + 49 + (dy-1)*48 + (dx-1)] : 0.f;
                d[(long)p_l*KC + (dy*3+dx)*512] = __float2bfloat16(v);
            }
        }
    }
}

// ---------------- conv weight repack: (Co,512,3,3) fp32 -> Co x (tap*512+ci) bf16 ----------------
__global__ __launch_bounds__(256) void convw_k(const float* __restrict__ src,
        bf16* __restrict__ dst, int total)
{
    int idx = blockIdx.x*256 + threadIdx.x;
    if (idx >= total) return;
    int co = idx / KC, r = idx - co*KC;
    int tap = r >> 9, ci = r & 511;
    dst[idx] = __float2bfloat16(src[(long)co*KC + ci*9 + tap]);
}

// ---------------- h (C,P) fp32 -> hcp16 (C,P) bf16 + hp16 (P,C) bf16 ----------------
__global__ __launch_bounds__(256) void prep_h_k(const float* __restrict__ h,
        bf16* __restrict__ hcp, bf16* __restrict__ hp)
{
    __shared__ float tile[64][65];
    const int i = blockIdx.z, p0 = blockIdx.x*64, c0 = blockIdx.y*64;
    const int t = threadIdx.x, tx = t&63, tq = t>>6;
    const float* src = h + (long)i*CP;
    #pragma unroll
    for (int s=0;s<16;++s){
        int r = tq + s*4;
        float v = src[(long)(c0+r)*PIX + p0 + tx];
        tile[r][tx] = v;
        hcp[(long)i*CP + (long)(c0+r)*PIX + p0 + tx] = __float2bfloat16(v);
    }
    __syncthreads();
    #pragma unroll
    for (int s=0;s<16;++s){
        int r = tq + s*4;
        hp[(long)i*CP + (long)(p0+r)*256 + c0 + tx] = __float2bfloat16(tile[tx][r]);
    }
}

// ---------------- attention weight conversion ----------------
__global__ __launch_bounds__(256) void convert_w_k(const float* __restrict__ wint,
    const float* __restrict__ wintra, const float* __restrict__ gw, bf16* __restrict__ o)
{
    int t = blockIdx.x*256 + threadIdx.x;
    int d = t >> 8, c = t & 255;
    o[t]          = __float2bfloat16(wint[c*256 + d]);
    o[65536 + t]  = __float2bfloat16(wintra[c*256 + d]);
    o[131072 + t] = __float2bfloat16(gw[t]);
}

// ---------------- row softmax in place on bf16 ----------------
__global__ __launch_bounds__(256) void softmax16_k(bf16* __restrict__ E)
{
    __shared__ float red[4], red2[4];
    const long base = (long)blockIdx.x * PIX;
    const int tid = threadIdx.x;
    float vv[9]; float mx = -1e30f;
    #pragma unroll
    for (int u=0;u<9;++u){ vv[u] = __bfloat162float(E[base + tid + u*256]); mx = fmaxf(mx, vv[u]); }
    for (int off=32; off; off>>=1) mx = fmaxf(mx, __shfl_xor(mx, off));
    if ((tid&63)==0) red[tid>>6] = mx;
    __syncthreads();
    mx = fmaxf(fmaxf(red[0],red[1]), fmaxf(red[2],red[3]));
    float s = 0.f;
    #pragma unroll
    for (int u=0;u<9;++u){ vv[u] = __expf(vv[u]-mx); s += vv[u]; }
    for (int off=32; off; off>>=1) s += __shfl_xor(s, off);
    if ((tid&63)==0) red2[tid>>6] = s;
    __syncthreads();
    s = red2[0]+red2[1]+red2[2]+red2[3];
    float inv = 1.f/s;
    #pragma unroll
    for (int u=0;u<9;++u) E[base + tid + u*256] = __float2bfloat16(vv[u]*inv);
}

__global__ __launch_bounds__(256) void gatesum_k(const float* __restrict__ g, float* __restrict__ out)
{
    int x = blockIdx.x*256 + threadIdx.x;
    float4 a = ((const float4*)g)[x];
    float4 b = ((const float4*)g)[x + CP/4];
    float4 c = ((const float4*)g)[x + CP/2];
    float4 r; r.x=a.x+b.x+c.x; r.y=a.y+b.y+c.y; r.z=a.z+b.z+c.z; r.w=a.w+b.w+c.w;
    ((float4*)out)[x] = r;
}

// ---------------- backbone ----------------
__global__ __launch_bounds__(256) void backbone_k(
    const float* __restrict__ frames, const float* __restrict__ W,
    const float* __restrict__ bias, float* __restrict__ v, float* __restrict__ h)
{
    __shared__ float wl[3*64*4];
    const int n = blockIdx.z, o0 = blockIdx.y * 4;
    const int p = blockIdx.x * 256 + threadIdx.x;
    const int y = p / 48, x = p % 48;
    for (int e = threadIdx.x; e < 768; e += 256) {
        int o_sel = e / 192, rem = e % 192, ci = rem / 64, k = rem % 64;
        wl[(ci*64 + k)*4 + o_sel] = W[((long)(o0 + o_sel)*3 + ci)*64 + k];
    }
    __syncthreads();
    float acc[4] = {0.f,0.f,0.f,0.f};
    for (int ci = 0; ci < 3; ++ci) {
        const float* src = frames + (((long)n*3 + ci)*384) * 384;
        #pragma unroll
        for (int k = 0; k < 64; ++k) {
            int ky = k >> 3, kx = k & 7;
            float iv = src[(8*y + ky)*384 + 8*x + kx];
            float4 w = ((const float4*)wl)[ci*64 + k];
            acc[0] += iv*w.x; acc[1] += iv*w.y; acc[2] += iv*w.z; acc[3] += iv*w.w;
        }
    }
    #pragma unroll
    for (int oo = 0; oo < 4; ++oo) {
        float r = fmaxf(acc[oo] + bias[o0 + oo], 0.f);
        long idx = ((long)n*CCH + o0 + oo)*PIX + p;
        v[idx] = r; h[idx] = r;
    }
}

__global__ __launch_bounds__(256) void rh_k(const float* __restrict__ rg, const float* __restrict__ h,
                                            float* __restrict__ rh)
{
    int idx = blockIdx.x*256 + threadIdx.x;
    rh[idx] = rg[idx]*h[idx];
}

__global__ __launch_bounds__(256) void hupd_k(const float* __restrict__ zg, const float* __restrict__ hc,
                                              float* __restrict__ h)
{
    int idx = blockIdx.x*256 + threadIdx.x;
    float z = zg[idx];
    h[idx] = (1.f - z)*h[idx] + z*hc[idx];
}

// ---------------- mask conv: split-K partials then reduce ----------------
__global__ __launch_bounds__(256) void maskpart_k(const float* __restrict__ yin,
        const float* __restrict__ W, float* __restrict__ part)
{
    __shared__ float wl[288];
    const int cb = blockIdx.y * 32;
    for (int e = threadIdx.x; e < 288; e += 256) wl[e] = W[cb*9 + e];
    __syncthreads();
    int id = blockIdx.x*256 + threadIdx.x;
    int n = id / PIX, p = id - n*PIX;
    int y = p / 48, x = p % 48;
    float acc = 0.f;
    for (int ci = 0; ci < 32; ++ci) {
        const float* src = yin + ((long)n*CCH + cb + ci)*PIX;
        #pragma unroll
        for (int dy = 0; dy < 3; ++dy) {
            int yy = y + dy - 1;
            #pragma unroll
            for (int dx = 0; dx < 3; ++dx) {
                int xx = x + dx - 1;
                float iv = (yy >= 0 && yy < 48 && xx >= 0 && xx < 48) ? src[yy*48 + xx] : 0.f;
                acc += iv * wl[ci*9 + dy*3 + dx];
            }
        }
    }
    part[(long)blockIdx.y*(3*PIX) + id] = acc;
}

__global__ __launch_bounds__(256) void maskred_k(const float* __restrict__ part,
        const float* __restrict__ bias, float* __restrict__ out)
{
    int id = blockIdx.x*256 + threadIdx.x;
    float acc = bias[0];
    #pragma unroll
    for (int s = 0; s < 8; ++s) acc += part[(long)s*(3*PIX) + id];
    out[id] = acc;
}

extern "C" void kernel_launch(void* const* d_in, const int* in_sizes, int n_in,
                              void* d_out, int out_size, void* d_ws, size_t ws_size,
                              hipStream_t stream)
{
    const float* frames     = (const float*)d_in[0];
    const float* backbone_w = (const float*)d_in[1];
    const float* backbone_b = (const float*)d_in[2];
    const float* W_intra    = (const float*)d_in[3];
    const float* W_inter    = (const float*)d_in[4];
    const float* gate_w     = (const float*)d_in[5];
    const float* gate_b     = (const float*)d_in[6];
    const float* Wz         = (const float*)d_in[7];
    const float* bz         = (const float*)d_in[8];
    const float* Wr         = (const float*)d_in[9];
    const float* br         = (const float*)d_in[10];
    const float* Wh         = (const float*)d_in[11];
    const float* bh         = (const float*)d_in[12];
    const float* ro_w1      = (const float*)d_in[13];
    const float* ro_b1      = (const float*)d_in[14];
    const float* ro_w2      = (const float*)d_in[15];
    const float* ro_b2      = (const float*)d_in[16];
    float* out = (float*)d_out;
    float* ws  = (float*)d_ws;

    float* h    = ws + 0L*NCP;
    float* v    = ws + 1L*NCP;
    float* magg = ws + 2L*NCP;
    float* zg   = ws + 3L*NCP;
    float* rg   = ws + 4L*NCP;
    float* rhg  = ws + 5L*NCP;   // rh (GRU) / gated (attention)
    float* hcmb = ws + 6L*NCP;   // hc (GRU) / Mb16 (attention)
    float* S    = ws + 7L*NCP;   // shared scratch: attention bufs OR im2col

    // attention-phase views of S
    float* E16f   = S;
    float* hp16f  = S + 7962624;
    float* hcp16f = hp16f + 884736;
    float* t16f   = hcp16f + 884736;
    float* ti16f  = t16f + 884736;
    // conv-phase view of S
    bf16* col16 = (bf16*)S;                 // 3*2304 x 4608 bf16 = 15,925,248 floats

    float* wbase = S + 15925248;
    bf16* Wint_t   = (bf16*)wbase;          // 3*65536 bf16
    bf16* Wintra_t = Wint_t + 65536;
    bf16* gatew16  = Wint_t + 131072;
    bf16* cw16     = (bf16*)(wbase + 98304); // 1024 x 4608 bf16 (Wz,Wr,Wh,ro_w1)
    float* mpart   = wbase + 98304 + 2359296; // 8 * 6912 floats

    bf16* E16    = (bf16*)E16f;
    bf16* hp16   = (bf16*)hp16f;
    bf16* hcp16  = (bf16*)hcp16f;
    bf16* t16    = (bf16*)t16f;
    bf16* ti16   = (bf16*)ti16f;
    bf16* Mb16   = (bf16*)hcmb;
    float* hc    = hcmb;
    float* gated = rhg;

    dim3 b256(256);

    backbone_k<<<dim3(9,64,3), b256, 0, stream>>>(frames, backbone_w, backbone_b, v, h);
    convert_w_k<<<dim3(256), b256, 0, stream>>>(W_inter, W_intra, gate_w, Wint_t);
    convw_k<<<dim3(4608), b256, 0, stream>>>(Wz, cw16, 256*KC);
    convw_k<<<dim3(4608), b256, 0, stream>>>(Wr, cw16 + 256L*KC, 256*KC);
    convw_k<<<dim3(4608), b256, 0, stream>>>(Wh, cw16 + 512L*KC, 256*KC);
    convw_k<<<dim3(4608), b256, 0, stream>>>(ro_w1, cw16 + 768L*KC, 256*KC);

    for (int it = 0; it < 3; ++it) {
        // ---- attention phase ----
        prep_h_k<<<dim3(36,4,3), b256, 0, stream>>>(h, hcp16, hp16);
        mgemm_k<0><<<dim3(54,2,1), b256, 0, stream>>>(hp16, hp16, -1, Wint_t, t16,
            nullptr, nullptr, 6912,256,256, 256,256,256, 0, 0L,0L,0L,0L);
        mgemm_k<0><<<dim3(54,2,1), b256, 0, stream>>>(hp16, hp16, -1, Wintra_t, ti16,
            nullptr, nullptr, 6912,256,256, 256,256,256, 0, 0L,0L,0L,0L);
        for (int i = 0; i < 3; ++i) {
            mgemm_k<0><<<dim3(18,18,3), b256, 0, stream>>>(t16 + (long)i*CP, ti16 + (long)i*CP, i,
                hp16, E16, nullptr, nullptr,
                2304,2304,256, 256,256,2304, 0, 0L,(long)CP,(long)PP,0L);
            softmax16_k<<<dim3(3*PIX), b256, 0, stream>>>(E16);
            mgemm_k<0><<<dim3(18,2,3), b256, 0, stream>>>(E16, E16, -1,
                hcp16, Mb16, nullptr, nullptr,
                2304,256,2304, 2304,2304,256, 0, (long)PP,(long)CP,(long)PIX*256,0L);
            mgemm_k<2><<<dim3(2,18,3), b256, 0, stream>>>(gatew16, gatew16, -1,
                Mb16, gated, Mb16, gate_b,
                256,2304,256, 256,256,PIX, 256, 0L,(long)PIX*256,(long)CP,(long)PIX*256);
            gatesum_k<<<dim3(576), b256, 0, stream>>>(gated, magg + (long)i*CP);
        }
        // ---- conv phase (im2col + MFMA) ----
        im2col_k<<<dim3(36,4,3), b256, 0, stream>>>(magg, col16, 0);
        im2col_k<<<dim3(36,4,3), b256, 0, stream>>>(h,    col16, 256);
        cgemm_k<1><<<dim3(4,54), b256, 0, stream>>>(cw16, col16, bz, br, zg, rg);
        rh_k<<<dim3(6912), b256, 0, stream>>>(rg, h, rhg);
        im2col_k<<<dim3(36,4,3), b256, 0, stream>>>(rhg, col16, 256);
        cgemm_k<2><<<dim3(2,54), b256, 0, stream>>>(cw16 + 512L*KC, col16, bh, nullptr, hc, nullptr);
        hupd_k<<<dim3(6912), b256, 0, stream>>>(zg, hc, h);
    }

    // ---- readout ----
    im2col_k<<<dim3(36,4,3), b256, 0, stream>>>(h, col16, 0);
    im2col_k<<<dim3(36,4,3), b256, 0, stream>>>(v, col16, 256);
    cgemm_k<3><<<dim3(2,54), b256, 0, stream>>>(cw16 + 768L*KC, col16, ro_b1, nullptr, zg, nullptr);
    maskpart_k<<<dim3(27,8), b256, 0, stream>>>(zg, ro_w2, mpart);
    maskred_k<<<dim3(27), b256, 0, stream>>>(mpart, ro_b2, out);
}

// Round 4
// 1626.850 us; speedup vs baseline: 10.5867x; 1.2187x over previous
//
#include <hip/hip_runtime.h>
#include <hip/hip_bf16.h>
#include <math.h>

#define PIX 2304
#define CCH 256
#define CP  589824      // CCH*PIX
#define NCP 1769472     // 3*CP
#define PP  5308416     // PIX*PIX
#define KC  4608        // conv K = 512*9

typedef __hip_bfloat16 bf16;
typedef __attribute__((ext_vector_type(8))) short bf16x8;
typedef __attribute__((ext_vector_type(4))) float f32x4;

__device__ __forceinline__ float sigmoidf_(float x){ return 1.f/(1.f+__expf(-x)); }

__device__ __forceinline__ void gl_lds16(const bf16* g, bf16* lds){
    __builtin_amdgcn_global_load_lds(
        (const __attribute__((address_space(1))) void*)g,
        (__attribute__((address_space(3))) void*)lds, 16, 0, 0);
}

// =======================================================================
// Unified bf16 MFMA GEMM, BT layout: C[m][n] = sum_k A[m][k]*B[n][k]
// BM=128 fixed, BN template (128 or 64). 2-phase double-buffered pipeline:
// stage tile t+1 before compute of tile t; one __syncthreads per K-step
// (its vmcnt(0) drain lands AFTER the MFMA phase -> latency hidden).
// blockIdx.z = kc*nzJ + jz  (jz batches, kc split-K chunk of size Ksub).
// EPI 0: bf16 out.   EPI 1: fp32 partial (offset kc*bsKc).
// EPI 2: fp32 sigmoid(acc+bias0[m]) * aux[n*auxld+m]  (gate).
// EPI 3: dual sigmoid conv out (m<256 -> o0/bias0 else o1/bias1), (img,co,p).
// EPI 4: tanh conv out.  EPI 5: relu conv out.
// =======================================================================
template<int EPI, int BN>
__global__ __launch_bounds__(256) void mgemm_k(
    const bf16* __restrict__ A0, const bf16* __restrict__ A1, int diagz,
    const bf16* __restrict__ B,
    float* __restrict__ o0, float* __restrict__ o1, bf16* __restrict__ ob,
    const bf16* __restrict__ aux,
    const float* __restrict__ bias0, const float* __restrict__ bias1,
    int M, int N, int lda, int ldb, int ldc, int auxld,
    long bsA, long bsB, long bsC, long bsAux,
    int nzJ, int Ksub, long bsKc)
{
    __shared__ bf16 As[2][128*64];
    __shared__ bf16 Bs[2][BN*64];
    const int z = blockIdx.z;
    const int jz = z % nzJ, kc = z / nzJ;
    const bf16* Ap = ((jz==diagz)?A1:A0) + jz*bsA + (long)blockIdx.x*128*lda;
    const bf16* Bp = B + jz*bsB + (long)blockIdx.y*BN*ldb;
    const int tid = threadIdx.x, l = tid & 63;
    const int wvu = tid & ~63;
    const int wr = tid>>7, wc = (tid>>6)&1;
    constexpr int NF = BN/32;           // n-frags per wave
    f32x4 acc[4][NF];
    #pragma unroll
    for (int i=0;i<4;++i)
        #pragma unroll
        for (int j=0;j<NF;++j) acc[i][j] = (f32x4){0.f,0.f,0.f,0.f};

    auto stage = [&](int buf, int kb){
        #pragma unroll
        for (int u=0;u<4;++u){
            int idx = u*256 + tid;
            gl_lds16(Ap + (long)(idx>>3)*lda + kb + (idx&7)*8, &As[buf][(u*256+wvu)*8]);
        }
        #pragma unroll
        for (int u=0;u<BN/32;++u){
            int idx = u*256 + tid;
            gl_lds16(Bp + (long)(idx>>3)*ldb + kb + (idx&7)*8, &Bs[buf][(u*256+wvu)*8]);
        }
    };

    const int kbeg = kc*Ksub;
    const int nk = Ksub >> 6;
    stage(0, kbeg);
    __syncthreads();
    for (int t=0; t<nk; ++t){
        const int cur = t & 1;
        if (t+1 < nk) stage(cur^1, kbeg + (t+1)*64);
        #pragma unroll
        for (int ks=0; ks<64; ks+=32){
            bf16x8 af[4], bfr[NF];
            #pragma unroll
            for (int i=0;i<4;++i)
                af[i] = *(const bf16x8*)&As[cur][(wr*64 + i*16 + (l&15))*64 + ks + (l>>4)*8];
            #pragma unroll
            for (int j=0;j<NF;++j)
                bfr[j] = *(const bf16x8*)&Bs[cur][(wc*(BN/2) + j*16 + (l&15))*64 + ks + (l>>4)*8];
            #pragma unroll
            for (int i=0;i<4;++i)
                #pragma unroll
                for (int j=0;j<NF;++j)
                    acc[i][j] = __builtin_amdgcn_mfma_f32_16x16x32_bf16(af[i], bfr[j], acc[i][j], 0,0,0);
        }
        __syncthreads();
    }

    const int mb = blockIdx.x*128 + wr*64, nb = blockIdx.y*BN + wc*(BN/2);
    #pragma unroll
    for (int i=0;i<4;++i)
        #pragma unroll
        for (int j=0;j<NF;++j){
            int gm0 = mb + i*16 + ((l>>4)<<2);
            int gn  = nb + j*16 + (l&15);
            int img = gn / 2304, p = gn - img*2304;   // for conv epilogues
            #pragma unroll
            for (int r=0;r<4;++r){
                int gm = gm0 + r;
                float vacc = acc[i][j][r];
                if (EPI==0){
                    ob[jz*bsC + (long)gm*ldc + gn] = __float2bfloat16(vacc);
                } else if (EPI==1){
                    o0[kc*bsKc + jz*bsC + (long)gm*ldc + gn] = vacc;
                } else if (EPI==2){
                    float g = sigmoidf_(vacc + bias0[gm]);
                    float mv = __bfloat162float(aux[jz*bsAux + (long)gn*auxld + gm]);
                    o0[jz*bsC + (long)gm*ldc + gn] = g*mv;
                } else if (EPI==3){
                    float* op; const float* bp; int co = gm;
                    if (co < 256){ op = o0; bp = bias0; }
                    else { op = o1; bp = bias1; co -= 256; }
                    op[(long)img*CP + (long)co*PIX + p] = sigmoidf_(vacc + bp[co]);
                } else if (EPI==4){
                    o0[(long)img*CP + (long)gm*PIX + p] = tanhf(vacc + bias0[gm]);
                } else {
                    o0[(long)img*CP + (long)gm*PIX + p] = fmaxf(vacc + bias0[gm], 0.f);
                }
            }
        }
}

// ---------------- reduce 2 split-K partial chunks -> bf16 Mb ----------------
__global__ __launch_bounds__(256) void mreduce_k(const float* __restrict__ part, bf16* __restrict__ o)
{
    int id = blockIdx.x*256 + threadIdx.x;          // float4 index, total 442368
    float4 a = ((const float4*)part)[id];
    float4 b = ((const float4*)part)[id + 442368];
    bf16 r[4];
    r[0] = __float2bfloat16(a.x+b.x); r[1] = __float2bfloat16(a.y+b.y);
    r[2] = __float2bfloat16(a.z+b.z); r[3] = __float2bfloat16(a.w+b.w);
    *(uint2*)&o[id*4] = *(uint2*)r;
}

// ---------------- im2col: src (3,256,2304) fp32 -> dst (3*2304, 4608) bf16 ----------------
__global__ __launch_bounds__(256) void im2col_k(const float* __restrict__ src,
        bf16* __restrict__ dst, int colofs)
{
    __shared__ float tile[64][163];
    const int p0 = blockIdx.x*64, cib = blockIdx.y*64, img = blockIdx.z;
    const int tid = threadIdx.x;
    const float* s = src + ((long)img*CCH + cib)*PIX;
    for (int e = tid; e < 64*162; e += 256){
        int ci_l = e / 162, off = e % 162;
        int gp = p0 + off - 49;
        tile[ci_l][off] = (gp >= 0 && gp < PIX) ? s[(long)ci_l*PIX + gp] : 0.f;
    }
    __syncthreads();
    const int ci_l = tid & 63, pg = tid >> 6;
    bf16* d = dst + ((long)img*PIX + p0)*KC + colofs + cib + ci_l;
    #pragma unroll
    for (int s8 = 0; s8 < 16; ++s8){
        int p_l = pg*16 + s8;
        int p = p0 + p_l, y = p / 48, x = p % 48;
        #pragma unroll
        for (int dy = 0; dy < 3; ++dy){
            int yy = y + dy - 1;
            #pragma unroll
            for (int dx = 0; dx < 3; ++dx){
                int xx = x + dx - 1;
                bool ok = (yy >= 0 && yy < 48 && xx >= 0 && xx < 48);
                float v = ok ? tile[ci_l][p_l + 49 + (dy-1)*48 + (dx-1)] : 0.f;
                d[(long)p_l*KC + (dy*3+dx)*512] = __float2bfloat16(v);
            }
        }
    }
}

// ---------------- conv weight repack: (Co,512,3,3) fp32 -> Co x (tap*512+ci) bf16 ----------------
__global__ __launch_bounds__(256) void convw_k(const float* __restrict__ src,
        bf16* __restrict__ dst, int total)
{
    int idx = blockIdx.x*256 + threadIdx.x;
    if (idx >= total) return;
    int co = idx / KC, r = idx - co*KC;
    int tap = r >> 9, ci = r & 511;
    dst[idx] = __float2bfloat16(src[(long)co*KC + ci*9 + tap]);
}

// ---------------- h (C,P) fp32 -> hcp16 (C,P) bf16 + hp16 (P,C) bf16 ----------------
__global__ __launch_bounds__(256) void prep_h_k(const float* __restrict__ h,
        bf16* __restrict__ hcp, bf16* __restrict__ hp)
{
    __shared__ float tile[64][65];
    const int i = blockIdx.z, p0 = blockIdx.x*64, c0 = blockIdx.y*64;
    const int t = threadIdx.x, tx = t&63, tq = t>>6;
    const float* src = h + (long)i*CP;
    #pragma unroll
    for (int s=0;s<16;++s){
        int r = tq + s*4;
        float v = src[(long)(c0+r)*PIX + p0 + tx];
        tile[r][tx] = v;
        hcp[(long)i*CP + (long)(c0+r)*PIX + p0 + tx] = __float2bfloat16(v);
    }
    __syncthreads();
    #pragma unroll
    for (int s=0;s<16;++s){
        int r = tq + s*4;
        hp[(long)i*CP + (long)(p0+r)*256 + c0 + tx] = __float2bfloat16(tile[tx][r]);
    }
}

// ---------------- attention weight conversion ----------------
__global__ __launch_bounds__(256) void convert_w_k(const float* __restrict__ wint,
    const float* __restrict__ wintra, const float* __restrict__ gw, bf16* __restrict__ o)
{
    int t = blockIdx.x*256 + threadIdx.x;
    int d = t >> 8, c = t & 255;
    o[t]          = __float2bfloat16(wint[c*256 + d]);
    o[65536 + t]  = __float2bfloat16(wintra[c*256 + d]);
    o[131072 + t] = __float2bfloat16(gw[t]);
}

// ---------------- row softmax in place on bf16 ----------------
__global__ __launch_bounds__(256) void softmax16_k(bf16* __restrict__ E)
{
    __shared__ float red[4], red2[4];
    const long base = (long)blockIdx.x * PIX;
    const int tid = threadIdx.x;
    float vv[9]; float mx = -1e30f;
    #pragma unroll
    for (int u=0;u<9;++u){ vv[u] = __bfloat162float(E[base + tid + u*256]); mx = fmaxf(mx, vv[u]); }
    for (int off=32; off; off>>=1) mx = fmaxf(mx, __shfl_xor(mx, off));
    if ((tid&63)==0) red[tid>>6] = mx;
    __syncthreads();
    mx = fmaxf(fmaxf(red[0],red[1]), fmaxf(red[2],red[3]));
    float s = 0.f;
    #pragma unroll
    for (int u=0;u<9;++u){ vv[u] = __expf(vv[u]-mx); s += vv[u]; }
    for (int off=32; off; off>>=1) s += __shfl_xor(s, off);
    if ((tid&63)==0) red2[tid>>6] = s;
    __syncthreads();
    s = red2[0]+red2[1]+red2[2]+red2[3];
    float inv = 1.f/s;
    #pragma unroll
    for (int u=0;u<9;++u) E[base + tid + u*256] = __float2bfloat16(vv[u]*inv);
}

__global__ __launch_bounds__(256) void gatesum_k(const float* __restrict__ g, float* __restrict__ out)
{
    int x = blockIdx.x*256 + threadIdx.x;
    float4 a = ((const float4*)g)[x];
    float4 b = ((const float4*)g)[x + CP/4];
    float4 c = ((const float4*)g)[x + CP/2];
    float4 r; r.x=a.x+b.x+c.x; r.y=a.y+b.y+c.y; r.z=a.z+b.z+c.z; r.w=a.w+b.w+c.w;
    ((float4*)out)[x] = r;
}

// ---------------- backbone ----------------
__global__ __launch_bounds__(256) void backbone_k(
    const float* __restrict__ frames, const float* __restrict__ W,
    const float* __restrict__ bias, float* __restrict__ v, float* __restrict__ h)
{
    __shared__ float wl[3*64*4];
    const int n = blockIdx.z, o0 = blockIdx.y * 4;
    const int p = blockIdx.x * 256 + threadIdx.x;
    const int y = p / 48, x = p % 48;
    for (int e = threadIdx.x; e < 768; e += 256) {
        int o_sel = e / 192, rem = e % 192, ci = rem / 64, k = rem % 64;
        wl[(ci*64 + k)*4 + o_sel] = W[((long)(o0 + o_sel)*3 + ci)*64 + k];
    }
    __syncthreads();
    float acc[4] = {0.f,0.f,0.f,0.f};
    for (int ci = 0; ci < 3; ++ci) {
        const float* src = frames + (((long)n*3 + ci)*384) * 384;
        #pragma unroll
        for (int k = 0; k < 64; ++k) {
            int ky = k >> 3, kx = k & 7;
            float iv = src[(8*y + ky)*384 + 8*x + kx];
            float4 w = ((const float4*)wl)[ci*64 + k];
            acc[0] += iv*w.x; acc[1] += iv*w.y; acc[2] += iv*w.z; acc[3] += iv*w.w;
        }
    }
    #pragma unroll
    for (int oo = 0; oo < 4; ++oo) {
        float r = fmaxf(acc[oo] + bias[o0 + oo], 0.f);
        long idx = ((long)n*CCH + o0 + oo)*PIX + p;
        v[idx] = r; h[idx] = r;
    }
}

__global__ __launch_bounds__(256) void rh_k(const float* __restrict__ rg, const float* __restrict__ h,
                                            float* __restrict__ rh)
{
    int idx = blockIdx.x*256 + threadIdx.x;
    rh[idx] = rg[idx]*h[idx];
}

__global__ __launch_bounds__(256) void hupd_k(const float* __restrict__ zg, const float* __restrict__ hc,
                                              float* __restrict__ h)
{
    int idx = blockIdx.x*256 + threadIdx.x;
    float z = zg[idx];
    h[idx] = (1.f - z)*h[idx] + z*hc[idx];
}

// ---------------- mask conv: split-K partials then reduce ----------------
__global__ __launch_bounds__(256) void maskpart_k(const float* __restrict__ yin,
        const float* __restrict__ W, float* __restrict__ part)
{
    __shared__ float wl[288];
    const int cb = blockIdx.y * 32;
    for (int e = threadIdx.x; e < 288; e += 256) wl[e] = W[cb*9 + e];
    __syncthreads();
    int id = blockIdx.x*256 + threadIdx.x;
    int n = id / PIX, p = id - n*PIX;
    int y = p / 48, x = p % 48;
    float acc = 0.f;
    for (int ci = 0; ci < 32; ++ci) {
        const float* src = yin + ((long)n*CCH + cb + ci)*PIX;
        #pragma unroll
        for (int dy = 0; dy < 3; ++dy) {
            int yy = y + dy - 1;
            #pragma unroll
            for (int dx = 0; dx < 3; ++dx) {
                int xx = x + dx - 1;
                float iv = (yy >= 0 && yy < 48 && xx >= 0 && xx < 48) ? src[yy*48 + xx] : 0.f;
                acc += iv * wl[ci*9 + dy*3 + dx];
            }
        }
    }
    part[(long)blockIdx.y*(3*PIX) + id] = acc;
}

__global__ __launch_bounds__(256) void maskred_k(const float* __restrict__ part,
        const float* __restrict__ bias, float* __restrict__ out)
{
    int id = blockIdx.x*256 + threadIdx.x;
    float acc = bias[0];
    #pragma unroll
    for (int s = 0; s < 8; ++s) acc += part[(long)s*(3*PIX) + id];
    out[id] = acc;
}

extern "C" void kernel_launch(void* const* d_in, const int* in_sizes, int n_in,
                              void* d_out, int out_size, void* d_ws, size_t ws_size,
                              hipStream_t stream)
{
    const float* frames     = (const float*)d_in[0];
    const float* backbone_w = (const float*)d_in[1];
    const float* backbone_b = (const float*)d_in[2];
    const float* W_intra    = (const float*)d_in[3];
    const float* W_inter    = (const float*)d_in[4];
    const float* gate_w     = (const float*)d_in[5];
    const float* gate_b     = (const float*)d_in[6];
    const float* Wz         = (const float*)d_in[7];
    const float* bz         = (const float*)d_in[8];
    const float* Wr         = (const float*)d_in[9];
    const float* br         = (const float*)d_in[10];
    const float* Wh         = (const float*)d_in[11];
    const float* bh         = (const float*)d_in[12];
    const float* ro_w1      = (const float*)d_in[13];
    const float* ro_b1      = (const float*)d_in[14];
    const float* ro_w2      = (const float*)d_in[15];
    const float* ro_b2      = (const float*)d_in[16];
    float* out = (float*)d_out;
    float* ws  = (float*)d_ws;

    float* h    = ws + 0L*NCP;
    float* v    = ws + 1L*NCP;
    float* magg = ws + 2L*NCP;
    float* zg   = ws + 3L*NCP;   // conv phase: z-gate | attn phase: M-gemm partials (with rg)
    float* rg   = ws + 4L*NCP;
    float* rhg  = ws + 5L*NCP;   // rh (GRU) / gated (attention)
    float* hcmb = ws + 6L*NCP;   // hc (GRU) / Mb16 (attention)
    float* S    = ws + 7L*NCP;   // attention bufs OR im2col (phase-aliased)

    float* E16f   = S;
    float* hp16f  = S + 7962624;
    float* hcp16f = hp16f + 884736;
    float* t16f   = hcp16f + 884736;
    float* ti16f  = t16f + 884736;
    bf16* col16 = (bf16*)S;                  // conv phase view (63.7 MB)

    float* wbase = S + 15925248;
    bf16* Wint_t   = (bf16*)wbase;
    bf16* Wintra_t = Wint_t + 65536;
    bf16* gatew16  = Wint_t + 131072;
    bf16* cw16     = (bf16*)(wbase + 98304);  // 1024 x 4608 bf16
    float* mpartM  = zg;                      // 2 chunks * 3j * 2304*256 fp32 = zg+rg
    float* maskp   = wbase + 98304 + 2359296;

    bf16* E16    = (bf16*)E16f;
    bf16* hp16   = (bf16*)hp16f;
    bf16* hcp16  = (bf16*)hcp16f;
    bf16* t16    = (bf16*)t16f;
    bf16* ti16   = (bf16*)ti16f;
    bf16* Mb16   = (bf16*)hcmb;
    float* hc    = hcmb;
    float* gated = rhg;

    dim3 b256(256);

    backbone_k<<<dim3(9,64,3), b256, 0, stream>>>(frames, backbone_w, backbone_b, v, h);
    convert_w_k<<<dim3(256), b256, 0, stream>>>(W_inter, W_intra, gate_w, Wint_t);
    convw_k<<<dim3(4608), b256, 0, stream>>>(Wz, cw16, 256*KC);
    convw_k<<<dim3(4608), b256, 0, stream>>>(Wr, cw16 + 256L*KC, 256*KC);
    convw_k<<<dim3(4608), b256, 0, stream>>>(Wh, cw16 + 512L*KC, 256*KC);
    convw_k<<<dim3(4608), b256, 0, stream>>>(ro_w1, cw16 + 768L*KC, 256*KC);

    for (int it = 0; it < 3; ++it) {
        // ---- attention phase ----
        prep_h_k<<<dim3(36,4,3), b256, 0, stream>>>(h, hcp16, hp16);
        // t/ti = hp * W  (M=6912,N=256,K=256), BN=64 -> 216 blocks
        mgemm_k<0,64><<<dim3(54,4,1), b256, 0, stream>>>(hp16, hp16, -1, Wint_t,
            nullptr, nullptr, t16, nullptr, nullptr, nullptr,
            6912,256, 256,256,256, 0, 0L,0L,0L,0L, 1, 256, 0L);
        mgemm_k<0,64><<<dim3(54,4,1), b256, 0, stream>>>(hp16, hp16, -1, Wintra_t,
            nullptr, nullptr, ti16, nullptr, nullptr, nullptr,
            6912,256, 256,256,256, 0, 0L,0L,0L,0L, 1, 256, 0L);
        for (int i = 0; i < 3; ++i) {
            // E_j[p][q] = sum_d A_i[p][d] * hp_j[q][d]
            mgemm_k<0,128><<<dim3(18,18,3), b256, 0, stream>>>(t16 + (long)i*CP, ti16 + (long)i*CP, i,
                hp16, nullptr, nullptr, E16, nullptr, nullptr, nullptr,
                2304,2304, 256,256,2304, 0, 0L,(long)CP,(long)PP,0L, 3, 256, 0L);
            softmax16_k<<<dim3(3*PIX), b256, 0, stream>>>(E16);
            // Mb_j[p][c] partials, split-K x2 (Ksub=1152): grid z = kc*3 + j
            mgemm_k<1,64><<<dim3(18,4,6), b256, 0, stream>>>(E16, E16, -1,
                hcp16, mpartM, nullptr, nullptr, nullptr, nullptr, nullptr,
                2304,256, 2304,2304,256, 0, (long)PP,(long)CP,(long)PIX*256,0L,
                3, 1152, 3L*PIX*256);
            mreduce_k<<<dim3(1728), b256, 0, stream>>>(mpartM, Mb16);
            // gated_j[c'][p] = sigmoid(gate) * Mb
            mgemm_k<2,64><<<dim3(2,36,3), b256, 0, stream>>>(gatew16, gatew16, -1,
                Mb16, gated, nullptr, nullptr, Mb16, gate_b, nullptr,
                256,2304, 256,256,PIX, 256, 0L,(long)PIX*256,(long)CP,(long)PIX*256,
                3, 256, 0L);
            gatesum_k<<<dim3(576), b256, 0, stream>>>(gated, magg + (long)i*CP);
        }
        // ---- conv phase (im2col + MFMA) ----
        im2col_k<<<dim3(36,4,3), b256, 0, stream>>>(magg, col16, 0);
        im2col_k<<<dim3(36,4,3), b256, 0, stream>>>(h,    col16, 256);
        mgemm_k<3,64><<<dim3(4,108,1), b256, 0, stream>>>(cw16, cw16, -1, col16,
            zg, rg, nullptr, nullptr, bz, br,
            512,6912, KC,KC,0, 0, 0L,0L,0L,0L, 1, KC, 0L);
        rh_k<<<dim3(6912), b256, 0, stream>>>(rg, h, rhg);
        im2col_k<<<dim3(36,4,3), b256, 0, stream>>>(rhg, col16, 256);
        mgemm_k<4,64><<<dim3(2,108,1), b256, 0, stream>>>(cw16 + 512L*KC, cw16, -1, col16,
            hc, nullptr, nullptr, nullptr, bh, nullptr,
            256,6912, KC,KC,0, 0, 0L,0L,0L,0L, 1, KC, 0L);
        hupd_k<<<dim3(6912), b256, 0, stream>>>(zg, hc, h);
    }

    // ---- readout ----
    im2col_k<<<dim3(36,4,3), b256, 0, stream>>>(h, col16, 0);
    im2col_k<<<dim3(36,4,3), b256, 0, stream>>>(v, col16, 256);
    mgemm_k<5,64><<<dim3(2,108,1), b256, 0, stream>>>(cw16 + 768L*KC, cw16, -1, col16,
        zg, nullptr, nullptr, nullptr, ro_b1, nullptr,
        256,6912, KC,KC,0, 0, 0L,0L,0L,0L, 1, KC, 0L);
    maskpart_k<<<dim3(27,8), b256, 0, stream>>>(zg, ro_w2, maskp);
    maskred_k<<<dim3(27), b256, 0, stream>>>(maskp, ro_b2, out);
}

// Round 5
// 1338.584 us; speedup vs baseline: 12.8666x; 1.2154x over previous
//
#include <hip/hip_runtime.h>
#include <hip/hip_bf16.h>
#include <math.h>

#define PIX 2304
#define CCH 256
#define CP  589824      // CCH*PIX
#define NCP 1769472     // 3*CP
#define PP  5308416     // PIX*PIX
#define KC  4608        // conv K = 512*9
#define PADR 2512       // padded rows per image (50*50=2500 used, 16B-friendly)

typedef __hip_bfloat16 bf16;
typedef __attribute__((ext_vector_type(8))) short bf16x8;
typedef __attribute__((ext_vector_type(4))) float f32x4;

__device__ __forceinline__ float sigmoidf_(float x){ return 1.f/(1.f+__expf(-x)); }

__device__ __forceinline__ void gl_lds16(const bf16* g, bf16* lds){
    __builtin_amdgcn_global_load_lds(
        (const __attribute__((address_space(1))) void*)g,
        (__attribute__((address_space(3))) void*)lds, 16, 0, 0);
}

// =======================================================================
// Unified bf16 MFMA GEMM, BT layout: C[m][n] = sum_k A[m][k]*B[n][k]
// XOR-swizzled LDS (rule 21: linear LDS dest, swizzled GLOBAL source + swizzled read).
// 2-phase double-buffer. blockIdx.z = kc*nzJ + jz.
// EPI 0: bf16 out. 1: fp32 partial (+kc*bsKc). 2: sigmoid-gate * aux.
// =======================================================================
template<int EPI, int BN>
__global__ __launch_bounds__(256) void mgemm_k(
    const bf16* __restrict__ A0, const bf16* __restrict__ A1, int diagz,
    const bf16* __restrict__ B,
    float* __restrict__ o0, bf16* __restrict__ ob,
    const bf16* __restrict__ aux, const float* __restrict__ bias0,
    int M, int N, int lda, int ldb, int ldc, int auxld,
    long bsA, long bsB, long bsC, long bsAux,
    int nzJ, int Ksub, long bsKc)
{
    __shared__ bf16 As[2][128*64];
    __shared__ bf16 Bs[2][BN*64];
    const int z = blockIdx.z;
    const int jz = z % nzJ, kc = z / nzJ;
    const bf16* Ap = ((jz==diagz)?A1:A0) + jz*bsA + (long)blockIdx.x*128*lda;
    const bf16* Bp = B + jz*bsB + (long)blockIdx.y*BN*ldb;
    const int tid = threadIdx.x, l = tid & 63;
    const int wvu = tid & ~63;
    const int wr = tid>>7, wc = (tid>>6)&1;
    constexpr int NF = BN/32;
    f32x4 acc[4][NF];
    #pragma unroll
    for (int i=0;i<4;++i)
        #pragma unroll
        for (int j=0;j<NF;++j) acc[i][j] = (f32x4){0.f,0.f,0.f,0.f};

    auto stage = [&](int buf, int kb){
        #pragma unroll
        for (int u=0;u<4;++u){
            int idx = u*256 + tid;
            int row = idx>>3, g = (idx&7) ^ (row&7);
            gl_lds16(Ap + (long)row*lda + kb + g*8, &As[buf][(u*256+wvu)*8]);
        }
        #pragma unroll
        for (int u=0;u<BN/32;++u){
            int idx = u*256 + tid;
            int row = idx>>3, g = (idx&7) ^ (row&7);
            gl_lds16(Bp + (long)row*ldb + kb + g*8, &Bs[buf][(u*256+wvu)*8]);
        }
    };

    const int kbeg = kc*Ksub;
    const int nk = Ksub >> 6;
    stage(0, kbeg);
    __syncthreads();
    for (int t=0; t<nk; ++t){
        const int cur = t & 1;
        if (t+1 < nk) stage(cur^1, kbeg + (t+1)*64);
        #pragma unroll
        for (int ks=0; ks<64; ks+=32){
            bf16x8 af[4], bfr[NF];
            #pragma unroll
            for (int i=0;i<4;++i){
                int row = wr*64 + i*16 + (l&15);
                af[i] = *(const bf16x8*)&As[cur][row*64 + ((((ks>>3)+(l>>4)) ^ (row&7))<<3)];
            }
            #pragma unroll
            for (int j=0;j<NF;++j){
                int row = wc*(BN/2) + j*16 + (l&15);
                bfr[j] = *(const bf16x8*)&Bs[cur][row*64 + ((((ks>>3)+(l>>4)) ^ (row&7))<<3)];
            }
            #pragma unroll
            for (int i=0;i<4;++i)
                #pragma unroll
                for (int j=0;j<NF;++j)
                    acc[i][j] = __builtin_amdgcn_mfma_f32_16x16x32_bf16(af[i], bfr[j], acc[i][j], 0,0,0);
        }
        __syncthreads();
    }

    const int mb = blockIdx.x*128 + wr*64, nb = blockIdx.y*BN + wc*(BN/2);
    #pragma unroll
    for (int i=0;i<4;++i)
        #pragma unroll
        for (int j=0;j<NF;++j){
            int gm0 = mb + i*16 + ((l>>4)<<2);
            int gn  = nb + j*16 + (l&15);
            #pragma unroll
            for (int r=0;r<4;++r){
                int gm = gm0 + r;
                float vacc = acc[i][j][r];
                if (EPI==0){
                    ob[jz*bsC + (long)gm*ldc + gn] = __float2bfloat16(vacc);
                } else if (EPI==1){
                    o0[kc*bsKc + jz*bsC + (long)gm*ldc + gn] = vacc;
                } else {
                    float g = sigmoidf_(vacc + bias0[gm]);
                    float mv = __bfloat162float(aux[jz*bsAux + (long)gn*auxld + gm]);
                    o0[jz*bsC + (long)gm*ldc + gn] = g*mv;
                }
            }
        }
}

// =======================================================================
// Implicit-GEMM 3x3 conv: C[m=pixel][n=co] = sum_{tap,ci} in[p'+shift(tap)][ci]*W[co][tap*512+ci]
// A = padded transposed input [3][PADR][512] bf16 (borders zero).
// B = repacked weights [N][4608] bf16. Split-K over blockIdx.z (2 chunks of 2304).
// Writes fp32 partials part[kc][gn][img*2304+m] (vectorized f32x4 on m).
// =======================================================================
__global__ __launch_bounds__(256) void cgemm2_k(
    const bf16* __restrict__ inpad, const bf16* __restrict__ W,
    float* __restrict__ part, int N)
{
    __shared__ bf16 As[2][128*64];
    __shared__ bf16 Bs[2][64*64];
    const int tid = threadIdx.x, l = tid & 63, wvu = tid & ~63;
    const int wr = tid>>7, wc = (tid>>6)&1;
    const int bx = blockIdx.x, by = blockIdx.y, kc = blockIdx.z;
    const int img = bx/18, m0 = (bx - img*18)*128;
    const bf16* Ab = inpad + (long)img*PADR*512;
    const bf16* Bb = W + (long)by*64*KC;
    f32x4 acc[4][2];
    #pragma unroll
    for (int i=0;i<4;++i){ acc[i][0]=(f32x4){0,0,0,0}; acc[i][1]=(f32x4){0,0,0,0}; }

    auto stageA = [&](int buf, int k0){
        int tap = k0 >> 9, ci0 = k0 & 511;
        int dy = tap/3, dx = tap - 3*dy;
        int shift = (dy-1)*50 + (dx-1);
        #pragma unroll
        for (int u=0;u<4;++u){
            int idx = u*256 + tid;
            int row = idx>>3;
            int om = m0 + row;
            int prow = om + 2*(om/48) + 51 + shift;
            int g = (idx&7) ^ (row&7);
            gl_lds16(Ab + (long)prow*512 + ci0 + g*8, &As[buf][(u*256+wvu)*8]);
        }
    };
    auto stageB = [&](int buf, int k0){
        #pragma unroll
        for (int u=0;u<2;++u){
            int idx = u*256 + tid;
            int row = idx>>3;
            int g = (idx&7) ^ (row&7);
            gl_lds16(Bb + (long)row*KC + k0 + g*8, &Bs[buf][(u*256+wvu)*8]);
        }
    };

    const int kbeg = kc*2304;
    stageA(0, kbeg); stageB(0, kbeg);
    __syncthreads();
    for (int t=0; t<36; ++t){
        const int cur = t & 1;
        if (t+1 < 36){ stageA(cur^1, kbeg+(t+1)*64); stageB(cur^1, kbeg+(t+1)*64); }
        #pragma unroll
        for (int ks=0; ks<64; ks+=32){
            bf16x8 af[4], bfr[2];
            #pragma unroll
            for (int i=0;i<4;++i){
                int row = wr*64 + i*16 + (l&15);
                af[i] = *(const bf16x8*)&As[cur][row*64 + ((((ks>>3)+(l>>4)) ^ (row&7))<<3)];
            }
            #pragma unroll
            for (int j=0;j<2;++j){
                int row = wc*32 + j*16 + (l&15);
                bfr[j] = *(const bf16x8*)&Bs[cur][row*64 + ((((ks>>3)+(l>>4)) ^ (row&7))<<3)];
            }
            #pragma unroll
            for (int i=0;i<4;++i)
                #pragma unroll
                for (int j=0;j<2;++j)
                    acc[i][j] = __builtin_amdgcn_mfma_f32_16x16x32_bf16(af[i], bfr[j], acc[i][j], 0,0,0);
        }
        __syncthreads();
    }

    float* pbase = part + (long)kc*N*6912 + (long)img*2304;
    #pragma unroll
    for (int i=0;i<4;++i)
        #pragma unroll
        for (int j=0;j<2;++j){
            int gm0 = m0 + wr*64 + i*16 + ((l>>4)<<2);
            int gn  = by*64 + wc*32 + j*16 + (l&15);
            *(f32x4*)&pbase[(long)gn*6912 + gm0] = acc[i][j];
        }
}

// ---- split-K reduce + bias + activation -> (img,c,p) fp32 ----
// ACT 1 sigmoid, 2 tanh, 3 relu. DUAL: c>=256 -> o1/b1.
template<int ACT, int DUAL>
__global__ __launch_bounds__(256) void cred_k(const float* __restrict__ part,
        const float* __restrict__ b0, const float* __restrict__ b1,
        float* __restrict__ o0, float* __restrict__ o1, int N)
{
    int id = blockIdx.x*256 + threadIdx.x;
    int c = id / 6912, g = id - c*6912;
    int img = g / 2304, p = g - img*2304;
    float v = part[id] + part[id + (long)N*6912];
    float* op; const float* bp; int co = c;
    if (DUAL && c >= 256){ op = o1; bp = b1; co = c-256; }
    else { op = o0; bp = b0; }
    float r = v + bp[co];
    if (ACT==1) r = sigmoidf_(r);
    else if (ACT==2) r = tanhf(r);
    else r = fmaxf(r, 0.f);
    op[(long)img*CP + (long)co*PIX + p] = r;
}

// ---- pad-transpose: (c,p) fp32 -> in16pad[img][p'][cofs+c] bf16 ----
__global__ __launch_bounds__(256) void padtr_k(const float* __restrict__ src,
        bf16* __restrict__ dst, int cofs)
{
    __shared__ float tile[64][65];
    const int img = blockIdx.z, p0 = blockIdx.x*64, c0 = blockIdx.y*64;
    const int t = threadIdx.x, tx = t&63, tq = t>>6;
    const float* s = src + (long)img*CP;
    #pragma unroll
    for (int u=0;u<16;++u){
        int r = tq + u*4;
        tile[r][tx] = s[(long)(c0+r)*PIX + p0 + tx];
    }
    __syncthreads();
    bf16* d = dst + (long)img*PADR*512 + cofs + c0;
    #pragma unroll
    for (int u=0;u<16;++u){
        int pl = tq + u*4;
        int p = p0 + pl;
        int prow = p + 2*(p/48) + 51;
        d[(long)prow*512 + tx] = __float2bfloat16(tile[tx][pl]);
    }
}

// ---- reduce 2 split-K partial chunks -> bf16 Mb ----
__global__ __launch_bounds__(256) void mreduce_k(const float* __restrict__ part, bf16* __restrict__ o)
{
    int id = blockIdx.x*256 + threadIdx.x;          // float4 index, total 442368
    float4 a = ((const float4*)part)[id];
    float4 b = ((const float4*)part)[id + 442368];
    bf16 r[4];
    r[0] = __float2bfloat16(a.x+b.x); r[1] = __float2bfloat16(a.y+b.y);
    r[2] = __float2bfloat16(a.z+b.z); r[3] = __float2bfloat16(a.w+b.w);
    *(uint2*)&o[id*4] = *(uint2*)r;
}

// ---- conv weight repack: (Co,512,3,3) fp32 -> Co x (tap*512+ci) bf16 ----
__global__ __launch_bounds__(256) void convw_k(const float* __restrict__ src,
        bf16* __restrict__ dst, int total)
{
    int idx = blockIdx.x*256 + threadIdx.x;
    if (idx >= total) return;
    int co = idx / KC, r = idx - co*KC;
    int tap = r >> 9, ci = r & 511;
    dst[idx] = __float2bfloat16(src[(long)co*KC + ci*9 + tap]);
}

// ---- h (C,P) fp32 -> hcp16 (C,P) bf16 + hp16 (P,C) bf16 ----
__global__ __launch_bounds__(256) void prep_h_k(const float* __restrict__ h,
        bf16* __restrict__ hcp, bf16* __restrict__ hp)
{
    __shared__ float tile[64][65];
    const int i = blockIdx.z, p0 = blockIdx.x*64, c0 = blockIdx.y*64;
    const int t = threadIdx.x, tx = t&63, tq = t>>6;
    const float* src = h + (long)i*CP;
    #pragma unroll
    for (int s=0;s<16;++s){
        int r = tq + s*4;
        float v = src[(long)(c0+r)*PIX + p0 + tx];
        tile[r][tx] = v;
        hcp[(long)i*CP + (long)(c0+r)*PIX + p0 + tx] = __float2bfloat16(v);
    }
    __syncthreads();
    #pragma unroll
    for (int s=0;s<16;++s){
        int r = tq + s*4;
        hp[(long)i*CP + (long)(p0+r)*256 + c0 + tx] = __float2bfloat16(tile[tx][r]);
    }
}

// ---- attention weight conversion ----
__global__ __launch_bounds__(256) void convert_w_k(const float* __restrict__ wint,
    const float* __restrict__ wintra, const float* __restrict__ gw, bf16* __restrict__ o)
{
    int t = blockIdx.x*256 + threadIdx.x;
    int d = t >> 8, c = t & 255;
    o[t]          = __float2bfloat16(wint[c*256 + d]);
    o[65536 + t]  = __float2bfloat16(wintra[c*256 + d]);
    o[131072 + t] = __float2bfloat16(gw[t]);
}

// ---- row softmax in place on bf16 ----
__global__ __launch_bounds__(256) void softmax16_k(bf16* __restrict__ E)
{
    __shared__ float red[4], red2[4];
    const long base = (long)blockIdx.x * PIX;
    const int tid = threadIdx.x;
    float vv[9]; float mx = -1e30f;
    #pragma unroll
    for (int u=0;u<9;++u){ vv[u] = __bfloat162float(E[base + tid + u*256]); mx = fmaxf(mx, vv[u]); }
    for (int off=32; off; off>>=1) mx = fmaxf(mx, __shfl_xor(mx, off));
    if ((tid&63)==0) red[tid>>6] = mx;
    __syncthreads();
    mx = fmaxf(fmaxf(red[0],red[1]), fmaxf(red[2],red[3]));
    float s = 0.f;
    #pragma unroll
    for (int u=0;u<9;++u){ vv[u] = __expf(vv[u]-mx); s += vv[u]; }
    for (int off=32; off; off>>=1) s += __shfl_xor(s, off);
    if ((tid&63)==0) red2[tid>>6] = s;
    __syncthreads();
    s = red2[0]+red2[1]+red2[2]+red2[3];
    float inv = 1.f/s;
    #pragma unroll
    for (int u=0;u<9;++u) E[base + tid + u*256] = __float2bfloat16(vv[u]*inv);
}

__global__ __launch_bounds__(256) void gatesum_k(const float* __restrict__ g, float* __restrict__ out)
{
    int x = blockIdx.x*256 + threadIdx.x;
    float4 a = ((const float4*)g)[x];
    float4 b = ((const float4*)g)[x + CP/4];
    float4 c = ((const float4*)g)[x + CP/2];
    float4 r; r.x=a.x+b.x+c.x; r.y=a.y+b.y+c.y; r.z=a.z+b.z+c.z; r.w=a.w+b.w+c.w;
    ((float4*)out)[x] = r;
}

// ---- backbone ----
__global__ __launch_bounds__(256) void backbone_k(
    const float* __restrict__ frames, const float* __restrict__ W,
    const float* __restrict__ bias, float* __restrict__ v, float* __restrict__ h)
{
    __shared__ float wl[3*64*4];
    const int n = blockIdx.z, o0 = blockIdx.y * 4;
    const int p = blockIdx.x * 256 + threadIdx.x;
    const int y = p / 48, x = p % 48;
    for (int e = threadIdx.x; e < 768; e += 256) {
        int o_sel = e / 192, rem = e % 192, ci = rem / 64, k = rem % 64;
        wl[(ci*64 + k)*4 + o_sel] = W[((long)(o0 + o_sel)*3 + ci)*64 + k];
    }
    __syncthreads();
    float acc[4] = {0.f,0.f,0.f,0.f};
    for (int ci = 0; ci < 3; ++ci) {
        const float* src = frames + (((long)n*3 + ci)*384) * 384;
        #pragma unroll
        for (int k = 0; k < 64; ++k) {
            int ky = k >> 3, kx = k & 7;
            float iv = src[(8*y + ky)*384 + 8*x + kx];
            float4 w = ((const float4*)wl)[ci*64 + k];
            acc[0] += iv*w.x; acc[1] += iv*w.y; acc[2] += iv*w.z; acc[3] += iv*w.w;
        }
    }
    #pragma unroll
    for (int oo = 0; oo < 4; ++oo) {
        float r = fmaxf(acc[oo] + bias[o0 + oo], 0.f);
        long idx = ((long)n*CCH + o0 + oo)*PIX + p;
        v[idx] = r; h[idx] = r;
    }
}

__global__ __launch_bounds__(256) void rh_k(const float* __restrict__ rg, const float* __restrict__ h,
                                            float* __restrict__ rh)
{
    int idx = blockIdx.x*256 + threadIdx.x;
    rh[idx] = rg[idx]*h[idx];
}

__global__ __launch_bounds__(256) void hupd_k(const float* __restrict__ zg, const float* __restrict__ hc,
                                              float* __restrict__ h)
{
    int idx = blockIdx.x*256 + threadIdx.x;
    float z = zg[idx];
    h[idx] = (1.f - z)*h[idx] + z*hc[idx];
}

// ---- mask conv: split-K partials then reduce ----
__global__ __launch_bounds__(256) void maskpart_k(const float* __restrict__ yin,
        const float* __restrict__ W, float* __restrict__ part)
{
    __shared__ float wl[288];
    const int cb = blockIdx.y * 32;
    for (int e = threadIdx.x; e < 288; e += 256) wl[e] = W[cb*9 + e];
    __syncthreads();
    int id = blockIdx.x*256 + threadIdx.x;
    int n = id / PIX, p = id - n*PIX;
    int y = p / 48, x = p % 48;
    float acc = 0.f;
    for (int ci = 0; ci < 32; ++ci) {
        const float* src = yin + ((long)n*CCH + cb + ci)*PIX;
        #pragma unroll
        for (int dy = 0; dy < 3; ++dy) {
            int yy = y + dy - 1;
            #pragma unroll
            for (int dx = 0; dx < 3; ++dx) {
                int xx = x + dx - 1;
                float iv = (yy >= 0 && yy < 48 && xx >= 0 && xx < 48) ? src[yy*48 + xx] : 0.f;
                acc += iv * wl[ci*9 + dy*3 + dx];
            }
        }
    }
    part[(long)blockIdx.y*(3*PIX) + id] = acc;
}

__global__ __launch_bounds__(256) void maskred_k(const float* __restrict__ part,
        const float* __restrict__ bias, float* __restrict__ out)
{
    int id = blockIdx.x*256 + threadIdx.x;
    float acc = bias[0];
    #pragma unroll
    for (int s = 0; s < 8; ++s) acc += part[(long)s*(3*PIX) + id];
    out[id] = acc;
}

extern "C" void kernel_launch(void* const* d_in, const int* in_sizes, int n_in,
                              void* d_out, int out_size, void* d_ws, size_t ws_size,
                              hipStream_t stream)
{
    const float* frames     = (const float*)d_in[0];
    const float* backbone_w = (const float*)d_in[1];
    const float* backbone_b = (const float*)d_in[2];
    const float* W_intra    = (const float*)d_in[3];
    const float* W_inter    = (const float*)d_in[4];
    const float* gate_w     = (const float*)d_in[5];
    const float* gate_b     = (const float*)d_in[6];
    const float* Wz         = (const float*)d_in[7];
    const float* bz         = (const float*)d_in[8];
    const float* Wr         = (const float*)d_in[9];
    const float* br         = (const float*)d_in[10];
    const float* Wh         = (const float*)d_in[11];
    const float* bh         = (const float*)d_in[12];
    const float* ro_w1      = (const float*)d_in[13];
    const float* ro_b1      = (const float*)d_in[14];
    const float* ro_w2      = (const float*)d_in[15];
    const float* ro_b2      = (const float*)d_in[16];
    float* out = (float*)d_out;
    float* ws  = (float*)d_ws;

    float* h    = ws + 0L*NCP;
    float* v    = ws + 1L*NCP;
    float* magg = ws + 2L*NCP;
    float* zg   = ws + 3L*NCP;   // attn phase: M-gemm partials (with rg)
    float* rg   = ws + 4L*NCP;
    float* rhg  = ws + 5L*NCP;   // rh (GRU) / gated (attention)
    float* hcmb = ws + 6L*NCP;   // hc (GRU) / Mb16 (attention)
    float* S    = ws + 7L*NCP;

    float* E16f   = S;                        // attn: 7,962,624 f | conv: partials (<=7,077,888 f)
    float* hp16f  = S + 7962624;
    float* hcp16f = hp16f + 884736;
    float* t16f   = hcp16f + 884736;
    float* ti16f  = t16f + 884736;
    float* wbase  = S + 11501568;
    bf16* Wint_t   = (bf16*)wbase;            // 3*65536 bf16
    bf16* Wintra_t = Wint_t + 65536;
    bf16* gatew16  = Wint_t + 131072;
    bf16* cw16     = (bf16*)(wbase + 98304);  // 1024 x 4608 bf16
    bf16* inpad    = (bf16*)(wbase + 98304 + 2359296); // 3*PADR*512 bf16 = 3,858,432
    float* maskp   = wbase + 98304 + 2359296 + 1929216;

    bf16* E16    = (bf16*)E16f;
    bf16* hp16   = (bf16*)hp16f;
    bf16* hcp16  = (bf16*)hcp16f;
    bf16* t16    = (bf16*)t16f;
    bf16* ti16   = (bf16*)ti16f;
    bf16* Mb16   = (bf16*)hcmb;
    float* hc    = hcmb;
    float* gated = rhg;
    float* mpartM = zg;                       // 2 chunks * 3 * 2304*256 = 2 NCP
    float* cpart  = E16f;                     // conv partials alias E region

    dim3 b256(256);

    hipMemsetAsync(inpad, 0, 3858432*sizeof(bf16), stream);  // zero pad borders
    backbone_k<<<dim3(9,64,3), b256, 0, stream>>>(frames, backbone_w, backbone_b, v, h);
    convert_w_k<<<dim3(256), b256, 0, stream>>>(W_inter, W_intra, gate_w, Wint_t);
    convw_k<<<dim3(4608), b256, 0, stream>>>(Wz, cw16, 256*KC);
    convw_k<<<dim3(4608), b256, 0, stream>>>(Wr, cw16 + 256L*KC, 256*KC);
    convw_k<<<dim3(4608), b256, 0, stream>>>(Wh, cw16 + 512L*KC, 256*KC);
    convw_k<<<dim3(4608), b256, 0, stream>>>(ro_w1, cw16 + 768L*KC, 256*KC);

    for (int it = 0; it < 3; ++it) {
        // ---- attention phase ----
        prep_h_k<<<dim3(36,4,3), b256, 0, stream>>>(h, hcp16, hp16);
        // t & ti batched: z=2 selects W (bsB) and output (bsC)
        mgemm_k<0,64><<<dim3(54,4,2), b256, 0, stream>>>(hp16, hp16, -1, Wint_t,
            nullptr, t16, nullptr, nullptr,
            6912,256, 256,256,256, 0, 0L,65536L,1769472L,0L, 2, 256, 0L);
        for (int i = 0; i < 3; ++i) {
            // E_j[p][q] = sum_d A_i[p][d] * hp_j[q][d]
            mgemm_k<0,128><<<dim3(18,18,3), b256, 0, stream>>>(t16 + (long)i*CP, ti16 + (long)i*CP, i,
                hp16, nullptr, E16, nullptr, nullptr,
                2304,2304, 256,256,2304, 0, 0L,(long)CP,(long)PP,0L, 3, 256, 0L);
            softmax16_k<<<dim3(3*PIX), b256, 0, stream>>>(E16);
            // Mb_j[p][c] partials, split-K x2 (Ksub=1152)
            mgemm_k<1,64><<<dim3(18,4,6), b256, 0, stream>>>(E16, E16, -1,
                hcp16, mpartM, nullptr, nullptr, nullptr,
                2304,256, 2304,2304,256, 0, (long)PP,(long)CP,(long)PIX*256,0L,
                3, 1152, 3L*PIX*256);
            mreduce_k<<<dim3(1728), b256, 0, stream>>>(mpartM, Mb16);
            // gated_j[c'][p] = sigmoid(gate) * Mb
            mgemm_k<2,64><<<dim3(2,36,3), b256, 0, stream>>>(gatew16, gatew16, -1,
                Mb16, gated, nullptr, Mb16, gate_b,
                256,2304, 256,256,PIX, 256, 0L,(long)PIX*256,(long)CP,(long)PIX*256,
                3, 256, 0L);
            gatesum_k<<<dim3(576), b256, 0, stream>>>(gated, magg + (long)i*CP);
        }
        // ---- conv phase (implicit GEMM) ----
        padtr_k<<<dim3(36,4,3), b256, 0, stream>>>(magg, inpad, 0);
        padtr_k<<<dim3(36,4,3), b256, 0, stream>>>(h,    inpad, 256);
        cgemm2_k<<<dim3(54,8,2), b256, 0, stream>>>(inpad, cw16, cpart, 512);
        cred_k<1,1><<<dim3(13824), b256, 0, stream>>>(cpart, bz, br, zg, rg, 512);
        rh_k<<<dim3(6912), b256, 0, stream>>>(rg, h, rhg);
        padtr_k<<<dim3(36,4,3), b256, 0, stream>>>(rhg, inpad, 256);
        cgemm2_k<<<dim3(54,4,2), b256, 0, stream>>>(inpad, cw16 + 512L*KC, cpart, 256);
        cred_k<2,0><<<dim3(6912), b256, 0, stream>>>(cpart, bh, nullptr, hc, nullptr, 256);
        hupd_k<<<dim3(6912), b256, 0, stream>>>(zg, hc, h);
    }

    // ---- readout ----
    padtr_k<<<dim3(36,4,3), b256, 0, stream>>>(h, inpad, 0);
    padtr_k<<<dim3(36,4,3), b256, 0, stream>>>(v, inpad, 256);
    cgemm2_k<<<dim3(54,4,2), b256, 0, stream>>>(inpad, cw16 + 768L*KC, cpart, 256);
    cred_k<3,0><<<dim3(6912), b256, 0, stream>>>(cpart, ro_b1, nullptr, zg, nullptr, 256);
    maskpart_k<<<dim3(27,8), b256, 0, stream>>>(zg, ro_w2, maskp);
    maskred_k<<<dim3(27), b256, 0, stream>>>(maskp, ro_b2, out);
}

// Round 6
// 1137.712 us; speedup vs baseline: 15.1383x; 1.1766x over previous
//
#include <hip/hip_runtime.h>
#include <hip/hip_bf16.h>
#include <math.h>

#define PIX 2304
#define CCH 256
#define CP  589824      // CCH*PIX
#define NCP 1769472     // 3*CP
#define KC  4608        // conv K = 512*9
#define PADR 2512       // padded rows per image

typedef __hip_bfloat16 bf16;
typedef __attribute__((ext_vector_type(8))) short bf16x8;
typedef __attribute__((ext_vector_type(4))) float f32x4;

__device__ __forceinline__ float sigmoidf_(float x){ return 1.f/(1.f+__expf(-x)); }

__device__ __forceinline__ void gl_lds16(const bf16* g, bf16* lds){
    __builtin_amdgcn_global_load_lds(
        (const __attribute__((address_space(1))) void*)g,
        (__attribute__((address_space(3))) void*)lds, 16, 0, 0);
}

// =======================================================================
// Fused flash attention over 9 (i,j) pairs. Q = t_i (ti_i on diagonal),
// K = hp_j (P x C), V^T = hcp_j (C x P). Out Mb9[z] = softmax(QK^T)V, bf16.
// Block: 512 thr (8 waves), QBLK=128 (16 rows/wave), KVBLK=64, dbuf LDS.
// =======================================================================
__global__ __launch_bounds__(512) void fattn_k(
    const bf16* __restrict__ T, const bf16* __restrict__ Ti,
    const bf16* __restrict__ Khp, const bf16* __restrict__ Vcp,
    bf16* __restrict__ Ob)
{
    __shared__ bf16 Ks[2][64*256];   // [q][d], chunk-swizzled (32 chunks/row)
    __shared__ bf16 Vs[2][256*64];   // [c][q], chunk-swizzled (8 chunks/row)
    __shared__ bf16 Ps[8][16*64];    // per-wave P, chunk-major
    const int z = blockIdx.z, i = z/3, j = z%3;
    const bf16* Q  = ((i==j)? Ti : T) + (long)i*CP;
    const bf16* Kp = Khp + (long)j*CP;
    const bf16* Vp = Vcp + (long)j*CP;
    const int tid = threadIdx.x, l = tid & 63, w = tid >> 6;
    const int q0 = blockIdx.x*128;

    // Q fragments in registers: rows q0+w*16+(l&15), k chunks of 32
    bf16x8 qf[8];
    {
        const bf16* qr = Q + (long)(q0 + w*16 + (l&15))*256 + (l>>4)*8;
        #pragma unroll
        for (int ks=0; ks<8; ++ks) qf[ks] = *(const bf16x8*)(qr + ks*32);
    }
    f32x4 oacc[16];
    #pragma unroll
    for (int nf=0; nf<16; ++nf) oacc[nf] = (f32x4){0.f,0.f,0.f,0.f};
    float mrun[4] = {-3e38f,-3e38f,-3e38f,-3e38f};
    float lrun[4] = {0.f,0.f,0.f,0.f};

    auto stage = [&](int buf, int t){
        const int kq = t*64;
        #pragma unroll
        for (int u=0; u<4; ++u){            // K tile: 64 q-rows x 256 d
            int idx = u*512 + tid;
            int rr = idx>>5, cc = idx&31;
            gl_lds16(Kp + (long)(kq+rr)*256 + ((cc ^ (rr&7))<<3),
                     &Ks[buf][(u*512 + (tid & ~63))*8]);
        }
        #pragma unroll
        for (int u=0; u<4; ++u){            // V^T tile: 256 c-rows x 64 q
            int idx = u*512 + tid;
            int rr = idx>>3, cc = idx&7;
            gl_lds16(Vp + (long)rr*2304 + kq + ((cc ^ (rr&7))<<3),
                     &Vs[buf][(u*512 + (tid & ~63))*8]);
        }
    };

    stage(0, 0);
    __syncthreads();
    for (int t=0; t<36; ++t){
        const int cur = t & 1;
        if (t+1 < 36) stage(cur^1, t+1);

        // ---- QK^T: S[16 rows][64 q] per wave ----
        f32x4 sacc[4];
        #pragma unroll
        for (int nf=0; nf<4; ++nf) sacc[nf] = (f32x4){0.f,0.f,0.f,0.f};
        #pragma unroll
        for (int ks=0; ks<8; ++ks){
            #pragma unroll
            for (int nf=0; nf<4; ++nf){
                int row = nf*16 + (l&15);
                int phys = (ks*4 + (l>>4)) ^ (row&7);
                bf16x8 b = *(const bf16x8*)&Ks[cur][row*256 + phys*8];
                sacc[nf] = __builtin_amdgcn_mfma_f32_16x16x32_bf16(qf[ks], b, sacc[nf], 0,0,0);
            }
        }

        // ---- online softmax (rows r of lane's group) ----
        float alpha[4];
        #pragma unroll
        for (int r=0; r<4; ++r){
            float v = fmaxf(fmaxf(sacc[0][r], sacc[1][r]), fmaxf(sacc[2][r], sacc[3][r]));
            v = fmaxf(v, __shfl_xor(v,1)); v = fmaxf(v, __shfl_xor(v,2));
            v = fmaxf(v, __shfl_xor(v,4)); v = fmaxf(v, __shfl_xor(v,8));
            float mn = fmaxf(mrun[r], v);
            alpha[r] = __expf(mrun[r] - mn);
            mrun[r] = mn;
            float rs = 0.f;
            #pragma unroll
            for (int nf=0; nf<4; ++nf){
                float p = __expf(sacc[nf][r] - mn);
                sacc[nf][r] = p; rs += p;
            }
            rs += __shfl_xor(rs,1); rs += __shfl_xor(rs,2);
            rs += __shfl_xor(rs,4); rs += __shfl_xor(rs,8);
            lrun[r] = lrun[r]*alpha[r] + rs;
        }
        // ---- P -> LDS (chunk-major: elem = (col>>3)*128 + row*8 + (col&7)) ----
        #pragma unroll
        for (int nf=0; nf<4; ++nf)
            #pragma unroll
            for (int r=0; r<4; ++r){
                int row = (l>>4)*4 + r;
                int col = nf*16 + (l&15);
                Ps[w][(col>>3)*128 + row*8 + (col&7)] = __float2bfloat16(sacc[nf][r]);
            }
        __asm__ volatile("" ::: "memory");
        // ---- rescale O ----
        #pragma unroll
        for (int nf=0; nf<16; ++nf)
            #pragma unroll
            for (int r=0; r<4; ++r) oacc[nf][r] *= alpha[r];
        // ---- PV: O[16 rows][256 c] += P * V ----
        #pragma unroll
        for (int ks2=0; ks2<2; ++ks2){
            bf16x8 pa = *(const bf16x8*)&Ps[w][(ks2*4 + (l>>4))*128 + (l&15)*8];
            #pragma unroll
            for (int nf=0; nf<16; ++nf){
                int row = nf*16 + (l&15);
                int phys = (ks2*4 + (l>>4)) ^ (row&7);
                bf16x8 bv = *(const bf16x8*)&Vs[cur][row*64 + phys*8];
                oacc[nf] = __builtin_amdgcn_mfma_f32_16x16x32_bf16(pa, bv, oacc[nf], 0,0,0);
            }
        }
        __syncthreads();
    }

    // ---- normalize + store ----
    #pragma unroll
    for (int r=0; r<4; ++r) lrun[r] = 1.f / lrun[r];
    bf16* ob = Ob + (long)z*CP;
    const int prow0 = q0 + w*16 + (l>>4)*4;
    #pragma unroll
    for (int nf=0; nf<16; ++nf){
        int c = nf*16 + (l&15);
        #pragma unroll
        for (int r=0; r<4; ++r)
            ob[(long)(prow0+r)*256 + c] = __float2bfloat16(oacc[nf][r]*lrun[r]);
    }
}

// =======================================================================
// Unified bf16 MFMA GEMM, BT layout: C[m][n] = sum_k A[m][k]*B[n][k]
// XOR-swizzled LDS, 2-phase dbuf. blockIdx.z = kc*nzJ + jz.
// EPI 0: bf16 out.  EPI 2: fp32 sigmoid(acc+bias0[m]) * aux[n*auxld+m].
// =======================================================================
template<int EPI, int BN>
__global__ __launch_bounds__(256) void mgemm_k(
    const bf16* __restrict__ A0, const bf16* __restrict__ A1, int diagz,
    const bf16* __restrict__ B,
    float* __restrict__ o0, bf16* __restrict__ ob,
    const bf16* __restrict__ aux, const float* __restrict__ bias0,
    int M, int N, int lda, int ldb, int ldc, int auxld,
    long bsA, long bsB, long bsC, long bsAux,
    int nzJ, int Ksub, long bsKc)
{
    __shared__ bf16 As[2][128*64];
    __shared__ bf16 Bs[2][BN*64];
    const int z = blockIdx.z;
    const int jz = z % nzJ, kc = z / nzJ;
    const bf16* Ap = ((jz==diagz)?A1:A0) + jz*bsA + (long)blockIdx.x*128*lda;
    const bf16* Bp = B + jz*bsB + (long)blockIdx.y*BN*ldb;
    const int tid = threadIdx.x, l = tid & 63;
    const int wvu = tid & ~63;
    const int wr = tid>>7, wc = (tid>>6)&1;
    constexpr int NF = BN/32;
    f32x4 acc[4][NF];
    #pragma unroll
    for (int i=0;i<4;++i)
        #pragma unroll
        for (int j=0;j<NF;++j) acc[i][j] = (f32x4){0.f,0.f,0.f,0.f};

    auto stage = [&](int buf, int kb){
        #pragma unroll
        for (int u=0;u<4;++u){
            int idx = u*256 + tid;
            int row = idx>>3, g = (idx&7) ^ (row&7);
            gl_lds16(Ap + (long)row*lda + kb + g*8, &As[buf][(u*256+wvu)*8]);
        }
        #pragma unroll
        for (int u=0;u<BN/32;++u){
            int idx = u*256 + tid;
            int row = idx>>3, g = (idx&7) ^ (row&7);
            gl_lds16(Bp + (long)row*ldb + kb + g*8, &Bs[buf][(u*256+wvu)*8]);
        }
    };

    const int kbeg = kc*Ksub;
    const int nk = Ksub >> 6;
    stage(0, kbeg);
    __syncthreads();
    for (int t=0; t<nk; ++t){
        const int cur = t & 1;
        if (t+1 < nk) stage(cur^1, kbeg + (t+1)*64);
        #pragma unroll
        for (int ks=0; ks<64; ks+=32){
            bf16x8 af[4], bfr[NF];
            #pragma unroll
            for (int i=0;i<4;++i){
                int row = wr*64 + i*16 + (l&15);
                af[i] = *(const bf16x8*)&As[cur][row*64 + ((((ks>>3)+(l>>4)) ^ (row&7))<<3)];
            }
            #pragma unroll
            for (int j=0;j<NF;++j){
                int row = wc*(BN/2) + j*16 + (l&15);
                bfr[j] = *(const bf16x8*)&Bs[cur][row*64 + ((((ks>>3)+(l>>4)) ^ (row&7))<<3)];
            }
            #pragma unroll
            for (int i=0;i<4;++i)
                #pragma unroll
                for (int j=0;j<NF;++j)
                    acc[i][j] = __builtin_amdgcn_mfma_f32_16x16x32_bf16(af[i], bfr[j], acc[i][j], 0,0,0);
        }
        __syncthreads();
    }

    const int mb = blockIdx.x*128 + wr*64, nb = blockIdx.y*BN + wc*(BN/2);
    #pragma unroll
    for (int i=0;i<4;++i)
        #pragma unroll
        for (int j=0;j<NF;++j){
            int gm0 = mb + i*16 + ((l>>4)<<2);
            int gn  = nb + j*16 + (l&15);
            #pragma unroll
            for (int r=0;r<4;++r){
                int gm = gm0 + r;
                float vacc = acc[i][j][r];
                if (EPI==0){
                    ob[jz*bsC + (long)gm*ldc + gn] = __float2bfloat16(vacc);
                } else {
                    float g = sigmoidf_(vacc + bias0[gm]);
                    float mv = __bfloat162float(aux[jz*bsAux + (long)gn*auxld + gm]);
                    o0[jz*bsC + (long)gm*ldc + gn] = g*mv;
                }
            }
        }
}

// =======================================================================
// Implicit-GEMM 3x3 conv (as round 5)
// =======================================================================
__global__ __launch_bounds__(256) void cgemm2_k(
    const bf16* __restrict__ inpad, const bf16* __restrict__ W,
    float* __restrict__ part, int N)
{
    __shared__ bf16 As[2][128*64];
    __shared__ bf16 Bs[2][64*64];
    const int tid = threadIdx.x, l = tid & 63, wvu = tid & ~63;
    const int wr = tid>>7, wc = (tid>>6)&1;
    const int bx = blockIdx.x, by = blockIdx.y, kc = blockIdx.z;
    const int img = bx/18, m0 = (bx - img*18)*128;
    const bf16* Ab = inpad + (long)img*PADR*512;
    const bf16* Bb = W + (long)by*64*KC;
    f32x4 acc[4][2];
    #pragma unroll
    for (int i=0;i<4;++i){ acc[i][0]=(f32x4){0,0,0,0}; acc[i][1]=(f32x4){0,0,0,0}; }

    auto stageA = [&](int buf, int k0){
        int tap = k0 >> 9, ci0 = k0 & 511;
        int dy = tap/3, dx = tap - 3*dy;
        int shift = (dy-1)*50 + (dx-1);
        #pragma unroll
        for (int u=0;u<4;++u){
            int idx = u*256 + tid;
            int row = idx>>3;
            int om = m0 + row;
            int prow = om + 2*(om/48) + 51 + shift;
            int g = (idx&7) ^ (row&7);
            gl_lds16(Ab + (long)prow*512 + ci0 + g*8, &As[buf][(u*256+wvu)*8]);
        }
    };
    auto stageB = [&](int buf, int k0){
        #pragma unroll
        for (int u=0;u<2;++u){
            int idx = u*256 + tid;
            int row = idx>>3;
            int g = (idx&7) ^ (row&7);
            gl_lds16(Bb + (long)row*KC + k0 + g*8, &Bs[buf][(u*256+wvu)*8]);
        }
    };

    const int kbeg = kc*2304;
    stageA(0, kbeg); stageB(0, kbeg);
    __syncthreads();
    for (int t=0; t<36; ++t){
        const int cur = t & 1;
        if (t+1 < 36){ stageA(cur^1, kbeg+(t+1)*64); stageB(cur^1, kbeg+(t+1)*64); }
        #pragma unroll
        for (int ks=0; ks<64; ks+=32){
            bf16x8 af[4], bfr[2];
            #pragma unroll
            for (int i=0;i<4;++i){
                int row = wr*64 + i*16 + (l&15);
                af[i] = *(const bf16x8*)&As[cur][row*64 + ((((ks>>3)+(l>>4)) ^ (row&7))<<3)];
            }
            #pragma unroll
            for (int j=0;j<2;++j){
                int row = wc*32 + j*16 + (l&15);
                bfr[j] = *(const bf16x8*)&Bs[cur][row*64 + ((((ks>>3)+(l>>4)) ^ (row&7))<<3)];
            }
            #pragma unroll
            for (int i=0;i<4;++i)
                #pragma unroll
                for (int j=0;j<2;++j)
                    acc[i][j] = __builtin_amdgcn_mfma_f32_16x16x32_bf16(af[i], bfr[j], acc[i][j], 0,0,0);
        }
        __syncthreads();
    }

    float* pbase = part + (long)kc*N*6912 + (long)img*2304;
    #pragma unroll
    for (int i=0;i<4;++i)
        #pragma unroll
        for (int j=0;j<2;++j){
            int gm0 = m0 + wr*64 + i*16 + ((l>>4)<<2);
            int gn  = by*64 + wc*32 + j*16 + (l&15);
            *(f32x4*)&pbase[(long)gn*6912 + gm0] = acc[i][j];
        }
}

template<int ACT, int DUAL>
__global__ __launch_bounds__(256) void cred_k(const float* __restrict__ part,
        const float* __restrict__ b0, const float* __restrict__ b1,
        float* __restrict__ o0, float* __restrict__ o1, int N)
{
    int id = blockIdx.x*256 + threadIdx.x;
    int c = id / 6912, g = id - c*6912;
    int img = g / 2304, p = g - img*2304;
    float v = part[id] + part[id + (long)N*6912];
    float* op; const float* bp; int co = c;
    if (DUAL && c >= 256){ op = o1; bp = b1; co = c-256; }
    else { op = o0; bp = b0; }
    float r = v + bp[co];
    if (ACT==1) r = sigmoidf_(r);
    else if (ACT==2) r = tanhf(r);
    else r = fmaxf(r, 0.f);
    op[(long)img*CP + (long)co*PIX + p] = r;
}

__global__ __launch_bounds__(256) void padtr_k(const float* __restrict__ src,
        bf16* __restrict__ dst, int cofs)
{
    __shared__ float tile[64][65];
    const int img = blockIdx.z, p0 = blockIdx.x*64, c0 = blockIdx.y*64;
    const int t = threadIdx.x, tx = t&63, tq = t>>6;
    const float* s = src + (long)img*CP;
    #pragma unroll
    for (int u=0;u<16;++u){
        int r = tq + u*4;
        tile[r][tx] = s[(long)(c0+r)*PIX + p0 + tx];
    }
    __syncthreads();
    bf16* d = dst + (long)img*PADR*512 + cofs + c0;
    #pragma unroll
    for (int u=0;u<16;++u){
        int pl = tq + u*4;
        int p = p0 + pl;
        int prow = p + 2*(p/48) + 51;
        d[(long)prow*512 + tx] = __float2bfloat16(tile[tx][pl]);
    }
}

__global__ __launch_bounds__(256) void convw_k(const float* __restrict__ src,
        bf16* __restrict__ dst, int total)
{
    int idx = blockIdx.x*256 + threadIdx.x;
    if (idx >= total) return;
    int co = idx / KC, r = idx - co*KC;
    int tap = r >> 9, ci = r & 511;
    dst[idx] = __float2bfloat16(src[(long)co*KC + ci*9 + tap]);
}

__global__ __launch_bounds__(256) void prep_h_k(const float* __restrict__ h,
        bf16* __restrict__ hcp, bf16* __restrict__ hp)
{
    __shared__ float tile[64][65];
    const int i = blockIdx.z, p0 = blockIdx.x*64, c0 = blockIdx.y*64;
    const int t = threadIdx.x, tx = t&63, tq = t>>6;
    const float* src = h + (long)i*CP;
    #pragma unroll
    for (int s=0;s<16;++s){
        int r = tq + s*4;
        float v = src[(long)(c0+r)*PIX + p0 + tx];
        tile[r][tx] = v;
        hcp[(long)i*CP + (long)(c0+r)*PIX + p0 + tx] = __float2bfloat16(v);
    }
    __syncthreads();
    #pragma unroll
    for (int s=0;s<16;++s){
        int r = tq + s*4;
        hp[(long)i*CP + (long)(p0+r)*256 + c0 + tx] = __float2bfloat16(tile[tx][r]);
    }
}

__global__ __launch_bounds__(256) void convert_w_k(const float* __restrict__ wint,
    const float* __restrict__ wintra, const float* __restrict__ gw, bf16* __restrict__ o)
{
    int t = blockIdx.x*256 + threadIdx.x;
    int d = t >> 8, c = t & 255;
    o[t]          = __float2bfloat16(wint[c*256 + d]);
    o[65536 + t]  = __float2bfloat16(wintra[c*256 + d]);
    o[131072 + t] = __float2bfloat16(gw[t]);
}

// ---- sum 3 gated pair-slabs (z = i*3+j) -> magg_i ----
__global__ __launch_bounds__(256) void gatesum_k(const float* __restrict__ g, float* __restrict__ out)
{
    int x = blockIdx.x*256 + threadIdx.x;
    int i = blockIdx.y;
    const float* gi = g + (long)i*3*CP;
    float4 a = ((const float4*)gi)[x];
    float4 b = ((const float4*)gi)[x + CP/4];
    float4 c = ((const float4*)gi)[x + CP/2];
    float4 r; r.x=a.x+b.x+c.x; r.y=a.y+b.y+c.y; r.z=a.z+b.z+c.z; r.w=a.w+b.w+c.w;
    ((float4*)(out + (long)i*CP))[x] = r;
}

__global__ __launch_bounds__(256) void backbone_k(
    const float* __restrict__ frames, const float* __restrict__ W,
    const float* __restrict__ bias, float* __restrict__ v, float* __restrict__ h)
{
    __shared__ float wl[3*64*4];
    const int n = blockIdx.z, o0 = blockIdx.y * 4;
    const int p = blockIdx.x * 256 + threadIdx.x;
    const int y = p / 48, x = p % 48;
    for (int e = threadIdx.x; e < 768; e += 256) {
        int o_sel = e / 192, rem = e % 192, ci = rem / 64, k = rem % 64;
        wl[(ci*64 + k)*4 + o_sel] = W[((long)(o0 + o_sel)*3 + ci)*64 + k];
    }
    __syncthreads();
    float acc[4] = {0.f,0.f,0.f,0.f};
    for (int ci = 0; ci < 3; ++ci) {
        const float* src = frames + (((long)n*3 + ci)*384) * 384;
        #pragma unroll
        for (int k = 0; k < 64; ++k) {
            int ky = k >> 3, kx = k & 7;
            float iv = src[(8*y + ky)*384 + 8*x + kx];
            float4 w = ((const float4*)wl)[ci*64 + k];
            acc[0] += iv*w.x; acc[1] += iv*w.y; acc[2] += iv*w.z; acc[3] += iv*w.w;
        }
    }
    #pragma unroll
    for (int oo = 0; oo < 4; ++oo) {
        float r = fmaxf(acc[oo] + bias[o0 + oo], 0.f);
        long idx = ((long)n*CCH + o0 + oo)*PIX + p;
        v[idx] = r; h[idx] = r;
    }
}

__global__ __launch_bounds__(256) void rh_k(const float* __restrict__ rg, const float* __restrict__ h,
                                            float* __restrict__ rh)
{
    int idx = blockIdx.x*256 + threadIdx.x;
    rh[idx] = rg[idx]*h[idx];
}

__global__ __launch_bounds__(256) void hupd_k(const float* __restrict__ zg, const float* __restrict__ hc,
                                              float* __restrict__ h)
{
    int idx = blockIdx.x*256 + threadIdx.x;
    float z = zg[idx];
    h[idx] = (1.f - z)*h[idx] + z*hc[idx];
}

__global__ __launch_bounds__(256) void maskpart_k(const float* __restrict__ yin,
        const float* __restrict__ W, float* __restrict__ part)
{
    __shared__ float wl[288];
    const int cb = blockIdx.y * 32;
    for (int e = threadIdx.x; e < 288; e += 256) wl[e] = W[cb*9 + e];
    __syncthreads();
    int id = blockIdx.x*256 + threadIdx.x;
    int n = id / PIX, p = id - n*PIX;
    int y = p / 48, x = p % 48;
    float acc = 0.f;
    for (int ci = 0; ci < 32; ++ci) {
        const float* src = yin + ((long)n*CCH + cb + ci)*PIX;
        #pragma unroll
        for (int dy = 0; dy < 3; ++dy) {
            int yy = y + dy - 1;
            #pragma unroll
            for (int dx = 0; dx < 3; ++dx) {
                int xx = x + dx - 1;
                float iv = (yy >= 0 && yy < 48 && xx >= 0 && xx < 48) ? src[yy*48 + xx] : 0.f;
                acc += iv * wl[ci*9 + dy*3 + dx];
            }
        }
    }
    part[(long)blockIdx.y*(3*PIX) + id] = acc;
}

__global__ __launch_bounds__(256) void maskred_k(const float* __restrict__ part,
        const float* __restrict__ bias, float* __restrict__ out)
{
    int id = blockIdx.x*256 + threadIdx.x;
    float acc = bias[0];
    #pragma unroll
    for (int s = 0; s < 8; ++s) acc += part[(long)s*(3*PIX) + id];
    out[id] = acc;
}

extern "C" void kernel_launch(void* const* d_in, const int* in_sizes, int n_in,
                              void* d_out, int out_size, void* d_ws, size_t ws_size,
                              hipStream_t stream)
{
    const float* frames     = (const float*)d_in[0];
    const float* backbone_w = (const float*)d_in[1];
    const float* backbone_b = (const float*)d_in[2];
    const float* W_intra    = (const float*)d_in[3];
    const float* W_inter    = (const float*)d_in[4];
    const float* gate_w     = (const float*)d_in[5];
    const float* gate_b     = (const float*)d_in[6];
    const float* Wz         = (const float*)d_in[7];
    const float* bz         = (const float*)d_in[8];
    const float* Wr         = (const float*)d_in[9];
    const float* br         = (const float*)d_in[10];
    const float* Wh         = (const float*)d_in[11];
    const float* bh         = (const float*)d_in[12];
    const float* ro_w1      = (const float*)d_in[13];
    const float* ro_b1      = (const float*)d_in[14];
    const float* ro_w2      = (const float*)d_in[15];
    const float* ro_b2      = (const float*)d_in[16];
    float* out = (float*)d_out;
    float* ws  = (float*)d_ws;

    float* h    = ws + 0L*NCP;
    float* v    = ws + 1L*NCP;
    float* magg = ws + 2L*NCP;
    float* zg   = ws + 3L*NCP;   // conv: z-gate | attn: gated[9] (zg..rhg = 3 NCP)
    float* rg   = ws + 4L*NCP;
    float* rhg  = ws + 5L*NCP;
    float* hcmb = ws + 6L*NCP;   // hc (GRU)
    float* S    = ws + 7L*NCP;

    float* Mb9f   = S;                        // attn: 9*CP bf16 = 2,654,208 f | conv: partials
    float* hp16f  = S + 7962624;
    float* hcp16f = hp16f + 884736;
    float* t16f   = hcp16f + 884736;
    float* ti16f  = t16f + 884736;
    float* wbase  = S + 11501568;
    bf16* Wint_t   = (bf16*)wbase;            // 3*65536 bf16
    bf16* Wintra_t = Wint_t + 65536;
    bf16* gatew16  = Wint_t + 131072;
    bf16* cw16     = (bf16*)(wbase + 98304);  // 1024 x 4608 bf16
    bf16* inpad    = (bf16*)(wbase + 98304 + 2359296);
    float* maskp   = wbase + 98304 + 2359296 + 1929216;

    bf16* Mb9    = (bf16*)Mb9f;
    bf16* hp16   = (bf16*)hp16f;
    bf16* hcp16  = (bf16*)hcp16f;
    bf16* t16    = (bf16*)t16f;
    bf16* ti16   = (bf16*)ti16f;
    float* hc    = hcmb;
    float* gated = zg;                        // 9*CP fp32 = zg+rg+rhg
    float* cpart = Mb9f;

    dim3 b256(256);

    hipMemsetAsync(inpad, 0, 3858432*sizeof(bf16), stream);
    backbone_k<<<dim3(9,64,3), b256, 0, stream>>>(frames, backbone_w, backbone_b, v, h);
    convert_w_k<<<dim3(256), b256, 0, stream>>>(W_inter, W_intra, gate_w, Wint_t);
    convw_k<<<dim3(4608), b256, 0, stream>>>(Wz, cw16, 256*KC);
    convw_k<<<dim3(4608), b256, 0, stream>>>(Wr, cw16 + 256L*KC, 256*KC);
    convw_k<<<dim3(4608), b256, 0, stream>>>(Wh, cw16 + 512L*KC, 256*KC);
    convw_k<<<dim3(4608), b256, 0, stream>>>(ro_w1, cw16 + 768L*KC, 256*KC);

    for (int it = 0; it < 3; ++it) {
        // ---- attention phase ----
        prep_h_k<<<dim3(36,4,3), b256, 0, stream>>>(h, hcp16, hp16);
        // t & ti batched: z selects W (bsB) and output (bsC)
        mgemm_k<0,64><<<dim3(54,4,2), b256, 0, stream>>>(hp16, hp16, -1, Wint_t,
            nullptr, t16, nullptr, nullptr,
            6912,256, 256,256,256, 0, 0L,65536L,1769472L,0L, 2, 256, 0L);
        // fused flash attention over all 9 pairs
        fattn_k<<<dim3(18,1,9), dim3(512), 0, stream>>>(t16, ti16, hp16, hcp16, Mb9);
        // gated[z][c'][p] = sigmoid(gate_w.Mb9[z] + gb) * Mb9[z]
        mgemm_k<2,64><<<dim3(2,36,9), b256, 0, stream>>>(gatew16, gatew16, -1,
            Mb9, gated, nullptr, Mb9, gate_b,
            256,2304, 256,256,PIX, 256, 0L,(long)CP,(long)CP,(long)CP,
            9, 256, 0L);
        gatesum_k<<<dim3(576,3), b256, 0, stream>>>(gated, magg);
        // ---- conv phase (implicit GEMM) ----
        padtr_k<<<dim3(36,4,3), b256, 0, stream>>>(magg, inpad, 0);
        padtr_k<<<dim3(36,4,3), b256, 0, stream>>>(h,    inpad, 256);
        cgemm2_k<<<dim3(54,8,2), b256, 0, stream>>>(inpad, cw16, cpart, 512);
        cred_k<1,1><<<dim3(13824), b256, 0, stream>>>(cpart, bz, br, zg, rg, 512);
        rh_k<<<dim3(6912), b256, 0, stream>>>(rg, h, rhg);
        padtr_k<<<dim3(36,4,3), b256, 0, stream>>>(rhg, inpad, 256);
        cgemm2_k<<<dim3(54,4,2), b256, 0, stream>>>(inpad, cw16 + 512L*KC, cpart, 256);
        cred_k<2,0><<<dim3(6912), b256, 0, stream>>>(cpart, bh, nullptr, hc, nullptr, 256);
        hupd_k<<<dim3(6912), b256, 0, stream>>>(zg, hc, h);
    }

    // ---- readout ----
    padtr_k<<<dim3(36,4,3), b256, 0, stream>>>(h, inpad, 0);
    padtr_k<<<dim3(36,4,3), b256, 0, stream>>>(v, inpad, 256);
    cgemm2_k<<<dim3(54,4,2), b256, 0, stream>>>(inpad, cw16 + 768L*KC, cpart, 256);
    cred_k<3,0><<<dim3(6912), b256, 0, stream>>>(cpart, ro_b1, nullptr, zg, nullptr, 256);
    maskpart_k<<<dim3(27,8), b256, 0, stream>>>(zg, ro_w2, maskp);
    maskred_k<<<dim3(27), b256, 0, stream>>>(maskp, ro_b2, out);
}